// Round 11
// baseline (126.544 us; speedup 1.0000x reference)
//
#include <hip/hip_runtime.h>
#include <hip/hip_bf16.h>
#include <math.h>

#define HH 256
#define NCC 128
#define SPWW 64
#define CST 8192
#define VV 10000
#define BBB 16
#define TTT 256
#define LOG2E 1.4426950408889634f
#define LN2 0.6931471805599453f

typedef __attribute__((ext_vector_type(8))) short short8;
typedef __attribute__((ext_vector_type(4))) float f32x4;
typedef unsigned short u16;

__device__ inline float bf2f(u16 u) {
    union { unsigned int i; float f; } v; v.i = ((unsigned int)u) << 16; return v.f;
}
__device__ inline u16 f2bf(float f) {
    __hip_bfloat16 h = __float2bfloat16(f);
    return *reinterpret_cast<u16*>(&h);
}
__device__ inline float ex2(float x) { return __builtin_amdgcn_exp2f(x); }
__device__ inline float lg2(float x) { return __builtin_amdgcn_logf(x); }   // v_log_f32 = log2

// ================= mega-setup: wtrans(96) + pwtrans(628) + embnext(128) + zero-startv(32) + wordlist(1) =================
struct SetupA {
    const float* Ws[6]; u16* Wt;
    const float* pw; u16* pwT;
    const float* e1n; const float* e2n; u16* e1nb; u16* e2nb;
    const int* w2s; int* counts; int* offsets; int* wlist;
    float* startv;
};
__global__ __launch_bounds__(256) void fhmm_setup(SetupA a)
{
    __shared__ float t[64][65];
    int blk = blockIdx.x, tid = threadIdx.x;
    if (blk < 96) {
        int z = blk >> 4, r = blk & 15;
        int k0 = (r & 3) * 64, n0 = (r >> 2) * 64;
        const float* W = a.Ws[z];
        u16* dst = a.Wt + (size_t)z * HH * HH;
        #pragma unroll
        for (int i = 0; i < 16; ++i) {
            int idx = tid + i * 256; int rr = idx >> 6, c = idx & 63;
            t[rr][c] = W[(k0 + rr) * HH + n0 + c];
        }
        __syncthreads();
        #pragma unroll
        for (int i = 0; i < 16; ++i) {
            int idx = tid + i * 256; int rr = idx >> 6, c = idx & 63;
            dst[(n0 + rr) * HH + k0 + c] = f2bf(t[c][rr]);
        }
    } else if (blk < 724) {
        int idx = blk - 96;
        int v0 = (idx % 157) * 64, k0 = (idx / 157) * 64;
        #pragma unroll
        for (int i = 0; i < 16; ++i) {
            int id2 = tid + i * 256; int rr = id2 >> 6, c = id2 & 63;   // rr:k, c:v
            int v = v0 + c;
            t[rr][c] = (v < VV) ? a.pw[(size_t)(k0 + rr) * VV + v] : 0.f;
        }
        __syncthreads();
        #pragma unroll
        for (int i = 0; i < 16; ++i) {
            int id2 = tid + i * 256; int rr = id2 >> 6, c = id2 & 63;   // rr:v, c:k
            int v = v0 + rr;
            if (v < VV) a.pwT[(size_t)v * HH + k0 + c] = f2bf(t[c][rr]);
        }
    } else if (blk < 852) {
        int idx = (blk - 724) * 256 + tid;
        if (idx < NCC * HH) a.e1nb[idx] = f2bf(a.e1n[idx]);
        if (idx < SPWW * HH) a.e2nb[idx] = f2bf(a.e2n[idx]);
    } else if (blk < 884) {
        int idx = (blk - 852) * 256 + tid;
        if (idx < CST) a.startv[idx] = 0.f;
    } else {
        __shared__ int cnt[NCC], off[NCC + 1], cur[NCC];
        if (tid < NCC) cnt[tid] = 0;
        __syncthreads();
        for (int v = tid; v < VV; v += 256)
            atomicAdd(&cnt[a.w2s[v * SPWW] >> 6], 1);
        __syncthreads();
        if (tid == 0) {
            int acc = 0;
            for (int c = 0; c < NCC; ++c) { off[c] = acc; acc += cnt[c]; }
            off[NCC] = acc;
        }
        __syncthreads();
        if (tid < NCC) cur[tid] = off[tid];
        __syncthreads();
        for (int v = tid; v < VV; v += 256) {
            int c = a.w2s[v * SPWW] >> 6;
            int pos = atomicAdd(&cur[c], 1);
            a.wlist[pos] = v;
        }
        if (tid < NCC) { a.counts[tid] = cnt[tid]; a.offsets[tid] = off[tid]; }
        if (tid == 0) a.offsets[NCC] = off[NCC];
    }
}

// ================= batched MFMA MLP (3 heads per launch) =================
// LAYER 0: X = bf16(se1+se2) computed on the fly, Y = relu(X@W+b)
// LAYER 1: X = X[h] (bf16), Y = (relu(X@W+b) + (se1+se2)) * oscale;
//          head 0: Y not stored; raw f32 output dotted with pw -> atomicAdd startv.
struct MlpA {
    const u16* X[3];
    const float* se1[3]; const float* se2[3];
    const u16* Wth[3];
    const float* bias[3];
    u16* Y[3];
    float oscale[3];
    const float* pw;
    float* startv;
};
template<int LAYER>
__global__ __launch_bounds__(256) void fhmm_mlp_batch(MlpA a)
{
    int hd = blockIdx.z;
    int m0 = blockIdx.x * 64, n0 = blockIdx.y * 64;
    __shared__ char Xs[32768];
    __shared__ char Ws[32768];
    int tid = threadIdx.x, w = tid >> 6, lane = tid & 63, lr = lane & 15, lg = lane >> 4;
    const char* wsrc = (const char*)(a.Wth[hd] + (size_t)n0 * HH);
    if (LAYER == 0) {
        const float* s1 = a.se1[hd];
        const float* s2 = a.se2[hd];
        #pragma unroll
        for (int i = 0; i < 8; ++i) {
            int cc = i * 256 + tid; int row = cc >> 5, tt = cc & 31;
            int gm = m0 + row, k = tt * 8;
            const float* p1 = s1 + (gm >> 6) * HH + k;
            const float* p2 = s2 + (gm & 63) * HH + k;
            u16 pk[8];
            #pragma unroll
            for (int e = 0; e < 8; ++e) pk[e] = f2bf(p1[e] + p2[e]);
            int dst = row * 512 + ((tt ^ (row & 7)) << 4);
            *(uint4*)&Xs[dst] = *(uint4*)pk;
            *(uint4*)&Ws[dst] = *(const uint4*)(wsrc + cc * 16);
        }
    } else {
        const char* xsrc = (const char*)(a.X[hd] + (size_t)m0 * HH);
        #pragma unroll
        for (int i = 0; i < 8; ++i) {
            int cc = i * 256 + tid; int row = cc >> 5, tt = cc & 31;
            int dst = row * 512 + ((tt ^ (row & 7)) << 4);
            *(uint4*)&Xs[dst] = *(const uint4*)(xsrc + cc * 16);
            *(uint4*)&Ws[dst] = *(const uint4*)(wsrc + cc * 16);
        }
    }
    __syncthreads();
    short8 bfr[8];
    int brow = w * 16 + lr, bb = brow * 512, bsw = (brow & 7) << 4;
    #pragma unroll
    for (int ks = 0; ks < 8; ++ks)
        bfr[ks] = *(const short8*)(Ws + bb + (((ks * 4 + lg) << 4) ^ bsw));
    int cb = w * 16 + lg * 4;
    f32x4 bv = *(const f32x4*)(a.bias[hd] + n0 + cb);
    float osc = a.oscale[hd];
    u16* Yp = a.Y[hd];
    #pragma unroll
    for (int rm = 0; rm < 4; ++rm) {
        f32x4 acc = {0.f, 0.f, 0.f, 0.f};
        int ar = rm * 16 + lr, ab = ar * 512, asw = (ar & 7) << 4;
        #pragma unroll
        for (int ks = 0; ks < 8; ++ks) {
            short8 af = *(const short8*)(Xs + ab + (((ks * 4 + lg) << 4) ^ asw));
            acc = __builtin_amdgcn_mfma_f32_16x16x32_bf16(bfr[ks], af, acc, 0, 0, 0);
        }
        int gm = m0 + rm * 16 + lr;
        if (LAYER == 1) {
            const float* r1 = a.se1[hd] + (gm >> 6) * HH + n0 + cb;
            const float* r2 = a.se2[hd] + (gm & 63) * HH + n0 + cb;
            float vals[4];
            #pragma unroll
            for (int e = 0; e < 4; ++e)
                vals[e] = fmaxf(acc[e] + bv[e], 0.f) + r1[e] + r2[e];
            if (hd == 0) {
                // start head: raw f32 dot with pw, reduce over lg, atomic per row
                const float* pwc = a.pw + n0 + cb;
                float dotp = vals[0] * pwc[0] + vals[1] * pwc[1]
                           + vals[2] * pwc[2] + vals[3] * pwc[3];
                dotp += __shfl_xor(dotp, 16);
                dotp += __shfl_xor(dotp, 32);
                if (lg == 0) atomicAdd(&a.startv[gm], dotp);
            } else {
                ushort4 o;
                #pragma unroll
                for (int e = 0; e < 4; ++e) ((u16*)&o)[e] = f2bf(vals[e] * osc);
                *(ushort4*)(Yp + (size_t)gm * HH + n0 + cb) = o;
            }
        } else {
            ushort4 o;
            #pragma unroll
            for (int e = 0; e < 4; ++e)
                ((u16*)&o)[e] = f2bf(fmaxf(acc[e] + bv[e], 0.f));
            *(ushort4*)(Yp + (size_t)gm * HH + n0 + cb) = o;
        }
    }
}

// ================= U/V GEMM + fused row-lse: one block = 64 rows, all 3 B-tiles =================
__global__ __launch_bounds__(256) void fhmm_gemm_uv_lse(
    const u16* __restrict__ Abf, const u16* __restrict__ e1n,
    const u16* __restrict__ e2n, float* __restrict__ U2, float* __restrict__ V2,
    float* __restrict__ lse_trans2)
{
    int m0 = blockIdx.x * 64;
    __shared__ char Xs[32768];
    __shared__ char Ws[32768];
    __shared__ float lmU[4][64], lsU[4][64], lmV[4][64], lsV[4][64];
    int tid = threadIdx.x, w = tid >> 6, lane = tid & 63, lr = lane & 15, lg = lane >> 4;
    const char* xsrc = (const char*)(Abf + (size_t)m0 * HH);
    #pragma unroll
    for (int i = 0; i < 8; ++i) {
        int cc = i * 256 + tid; int row = cc >> 5, tt = cc & 31;
        int dst = row * 512 + ((tt ^ (row & 7)) << 4);
        *(uint4*)&Xs[dst] = *(const uint4*)(xsrc + cc * 16);
    }

    float mU[4], sU[4], mV[4], sV[4];
    #pragma unroll
    for (int rm = 0; rm < 4; ++rm) { mU[rm] = -3e38f; sU[rm] = 0.f; mV[rm] = -3e38f; sV[rm] = 0.f; }

    int cb = w * 16 + lg * 4;
    for (int y = 0; y < 3; ++y) {
        const char* wsrc = (y < 2) ? (const char*)(e1n + (size_t)y * 64 * HH)
                                   : (const char*)e2n;
        __syncthreads();
        #pragma unroll
        for (int i = 0; i < 8; ++i) {
            int cc = i * 256 + tid; int row = cc >> 5, tt = cc & 31;
            int dst = row * 512 + ((tt ^ (row & 7)) << 4);
            *(uint4*)&Ws[dst] = *(const uint4*)(wsrc + cc * 16);
        }
        __syncthreads();
        short8 bfr[8];
        int brow = w * 16 + lr, bb = brow * 512, bsw = (brow & 7) << 4;
        #pragma unroll
        for (int ks = 0; ks < 8; ++ks)
            bfr[ks] = *(const short8*)(Ws + bb + (((ks * 4 + lg) << 4) ^ bsw));
        #pragma unroll
        for (int rm = 0; rm < 4; ++rm) {
            f32x4 acc = {0.f, 0.f, 0.f, 0.f};
            int ar = rm * 16 + lr, ab = ar * 512, asw = (ar & 7) << 4;
            #pragma unroll
            for (int ks = 0; ks < 8; ++ks) {
                short8 af = *(const short8*)(Xs + ab + (((ks * 4 + lg) << 4) ^ asw));
                acc = __builtin_amdgcn_mfma_f32_16x16x32_bf16(bfr[ks], af, acc, 0, 0, 0);
            }
            int gm = m0 + rm * 16 + lr;
            float lm = fmaxf(fmaxf(acc[0], acc[1]), fmaxf(acc[2], acc[3]));
            if (y < 2) {
                *(f32x4*)(U2 + (size_t)gm * NCC + y * 64 + cb) = acc;
                float mn = fmaxf(mU[rm], lm);
                sU[rm] = sU[rm] * ex2(mU[rm] - mn)
                       + ex2(acc[0] - mn) + ex2(acc[1] - mn)
                       + ex2(acc[2] - mn) + ex2(acc[3] - mn);
                mU[rm] = mn;
            } else {
                *(f32x4*)(V2 + (size_t)gm * SPWW + cb) = acc;
                float mn = fmaxf(mV[rm], lm);
                sV[rm] = sV[rm] * ex2(mV[rm] - mn)
                       + ex2(acc[0] - mn) + ex2(acc[1] - mn)
                       + ex2(acc[2] - mn) + ex2(acc[3] - mn);
                mV[rm] = mn;
            }
        }
    }

    // reduce over lg (cols within wave), then across waves via LDS
    #pragma unroll
    for (int rm = 0; rm < 4; ++rm) {
        #pragma unroll
        for (int d = 16; d < 64; d <<= 1) {
            float m2 = __shfl_xor(mU[rm], d), sx = __shfl_xor(sU[rm], d);
            float mn = fmaxf(mU[rm], m2);
            sU[rm] = sU[rm] * ex2(mU[rm] - mn) + sx * ex2(m2 - mn); mU[rm] = mn;
            m2 = __shfl_xor(mV[rm], d); sx = __shfl_xor(sV[rm], d);
            mn = fmaxf(mV[rm], m2);
            sV[rm] = sV[rm] * ex2(mV[rm] - mn) + sx * ex2(m2 - mn); mV[rm] = mn;
        }
    }
    __syncthreads();
    if (lg == 0) {
        #pragma unroll
        for (int rm = 0; rm < 4; ++rm) {
            lmU[w][rm * 16 + lr] = mU[rm]; lsU[w][rm * 16 + lr] = sU[rm];
            lmV[w][rm * 16 + lr] = mV[rm]; lsV[w][rm * 16 + lr] = sV[rm];
        }
    }
    __syncthreads();
    if (tid < 64) {
        float MU = lmU[0][tid], SU = lsU[0][tid];
        float MV = lmV[0][tid], SV = lsV[0][tid];
        #pragma unroll
        for (int q = 1; q < 4; ++q) {
            float m2 = lmU[q][tid], sx = lsU[q][tid];
            float mn = fmaxf(MU, m2);
            SU = SU * ex2(MU - mn) + sx * ex2(m2 - mn); MU = mn;
            m2 = lmV[q][tid]; sx = lsV[q][tid];
            mn = fmaxf(MV, m2);
            SV = SV * ex2(MV - mn) + sx * ex2(m2 - mn); MV = mn;
        }
        lse_trans2[m0 + tid] = (MU + lg2(SU)) + (MV + lg2(SV));
    }
}

// ---------------- per-class emission GEMM + fused per-state lse (base-2) ----------------
__global__ __launch_bounds__(256) void fhmm_ew_mfma(
    const u16* __restrict__ hpre_bf, const u16* __restrict__ pwT,
    const float* __restrict__ pb, const int* __restrict__ wlist,
    const int* __restrict__ counts, const int* __restrict__ offsets,
    float* __restrict__ Ew2, float* __restrict__ lse_em2)
{
    int c = blockIdx.x;
    int cnt = counts[c], off = offsets[c];
    __shared__ char Hs[32768];
    __shared__ float emM[4][64], emS[4][64];
    int tid = threadIdx.x, w = tid >> 6, lane = tid & 63, lr = lane & 15, lg = lane >> 4;
    const char* src = (const char*)(hpre_bf + (size_t)c * 64 * HH);
    #pragma unroll
    for (int i = 0; i < 8; ++i) {
        int cc = i * 256 + tid; int row = cc >> 5, tt = cc & 31;
        *(uint4*)&Hs[row * 512 + ((tt ^ (row & 7)) << 4)] = *(const uint4*)(src + cc * 16);
    }
    __syncthreads();

    float em_m[4][4], em_s[4][4];
    #pragma unroll
    for (int rm = 0; rm < 4; ++rm)
        #pragma unroll
        for (int e = 0; e < 4; ++e) { em_m[rm][e] = -3e38f; em_s[rm][e] = 0.f; }

    for (int ch = 0; ch * 64 < cnt; ++ch) {
        int widx = ch * 64 + w * 16 + lr;
        bool valid = widx < cnt;
        int v = valid ? wlist[off + widx] : 0;
        short8 bw[8];
        short8 bz = {0, 0, 0, 0, 0, 0, 0, 0};
        #pragma unroll
        for (int ks = 0; ks < 8; ++ks)
            bw[ks] = valid ? *(const short8*)(pwT + (size_t)v * HH + ks * 32 + lg * 8) : bz;
        float pbv = valid ? pb[v] : 0.f;
        #pragma unroll
        for (int rm = 0; rm < 4; ++rm) {
            f32x4 acc = {0.f, 0.f, 0.f, 0.f};
            int ar = rm * 16 + lr, ab = ar * 512, asw = (ar & 7) << 4;
            #pragma unroll
            for (int ks = 0; ks < 8; ++ks) {
                short8 ah = *(const short8*)(Hs + ab + (((ks * 4 + lg) << 4) ^ asw));
                acc = __builtin_amdgcn_mfma_f32_16x16x32_bf16(ah, bw[ks], acc, 0, 0, 0);
            }
            f32x4 o;
            #pragma unroll
            for (int e = 0; e < 4; ++e) o[e] = (acc[e] + pbv) * LOG2E;
            if (valid)
                *(f32x4*)(Ew2 + (size_t)v * 64 + rm * 16 + lg * 4) = o;
            #pragma unroll
            for (int e = 0; e < 4; ++e) {
                if (valid) {
                    float mn = fmaxf(em_m[rm][e], o[e]);
                    em_s[rm][e] = em_s[rm][e] * ex2(em_m[rm][e] - mn) + ex2(o[e] - mn);
                    em_m[rm][e] = mn;
                }
            }
        }
    }

    #pragma unroll
    for (int rm = 0; rm < 4; ++rm)
        #pragma unroll
        for (int e = 0; e < 4; ++e) {
            float mm = em_m[rm][e], ss = em_s[rm][e];
            #pragma unroll
            for (int d = 1; d < 16; d <<= 1) {
                float m2 = __shfl_xor(mm, d);
                float s2 = __shfl_xor(ss, d);
                float mn = fmaxf(mm, m2);
                ss = ss * ex2(mm - mn) + s2 * ex2(m2 - mn);
                mm = mn;
            }
            em_m[rm][e] = mm; em_s[rm][e] = ss;
        }
    if (lr == 0) {
        #pragma unroll
        for (int rm = 0; rm < 4; ++rm)
            #pragma unroll
            for (int e = 0; e < 4; ++e) {
                emM[w][rm * 16 + lg * 4 + e] = em_m[rm][e];
                emS[w][rm * 16 + lg * 4 + e] = em_s[rm][e];
            }
    }
    __syncthreads();
    if (tid < 64) {
        float M = emM[0][tid], S = emS[0][tid];
        #pragma unroll
        for (int q2 = 1; q2 < 4; ++q2) {
            float m2 = emM[q2][tid], s2 = emS[q2][tid];
            float mn = fmaxf(M, m2);
            S = S * ex2(M - mn) + s2 * ex2(m2 - mn); M = mn;
        }
        lse_em2[c * 64 + tid] = M + lg2(fmaxf(S, 1e-33f));
    }
}

// ================= 4-ARY TREE COMBINE in lse2 semiring (obs computed inline) ==================
// LEAF=1: M_t[i][j] = U2[sr+i][c_t] - lse2[sr+i] + V2[sr+i][j] + Ew2[v_t*64+j] - lse_em2[64c_t+j]
template<int LEAF>
__global__ __launch_bounds__(256) void fhmm_combine4(
    const float* __restrict__ U2, const float* __restrict__ V2,
    const float* __restrict__ Ew2, const float* __restrict__ lse_em2,
    const float* __restrict__ lse2,
    const int* __restrict__ text, const int* __restrict__ w2s,
    const float* __restrict__ Lin, float* __restrict__ Lout)
{
    int p = blockIdx.x, b = blockIdx.y;
    int nodes = gridDim.x;
    int tid = threadIdx.x;
    int l6 = tid & 63, q = tid >> 6;

    __shared__ float Rb[64][65];
    __shared__ char Ps[8192], Qs[8192];
    __shared__ float mA2[64], mB2[64], mAf[64], mBf[64];
    __shared__ float part[2][4][64];
    __shared__ float rtB_l[64];

    int nm = LEAF ? ((p == 63) ? 3 : 4) : 4;
    int t0 = 4 * p + 1;
    int in0 = 4 * p;

    float va[16];
    float rowA = 0.f;

    if (LEAF) {
        int vprev = text[b * TTT + (t0 - 1)];
        int vA = text[b * TTT + t0];
        int srA = w2s[vprev * SPWW];
        int sA = w2s[vA * SPWW];          // = 64*cA
        int cA = sA >> 6;
        rowA = U2[(size_t)(srA + l6) * NCC + cA] - lse2[srA + l6];
        const float* vrow = V2 + (size_t)(srA + l6) * SPWW;
        const float* ewA = Ew2 + (size_t)vA * 64;
        const float* leA = lse_em2 + sA;
        #pragma unroll
        for (int jj = 0; jj < 16; ++jj) {
            int j = q * 16 + jj;
            va[jj] = vrow[j] + ewA[j] - leA[j];
        }
    } else {
        const float* Af = Lin + ((size_t)(b * (4 * nodes) + in0)) * 4096;
        #pragma unroll
        for (int jj = 0; jj < 16; ++jj)
            va[jj] = Af[l6 * 64 + q * 16 + jj];
    }

    for (int s = 1; s < nm; ++s) {
        float mloc = -3e38f;
        #pragma unroll
        for (int jj = 0; jj < 16; ++jj) mloc = fmaxf(mloc, va[jj]);
        part[0][q][l6] = mloc;

        float vb[16], obB = 0.f;
        if (LEAF) {
            int tB = t0 + s;
            int vBp = text[b * TTT + (tB - 1)];
            int vB = text[b * TTT + tB];
            int srB = w2s[vBp * SPWW];
            int sB = w2s[vB * SPWW];
            int cB = sB >> 6;
            if (tid < 64)
                rtB_l[tid] = U2[(size_t)(srB + tid) * NCC + cB] - lse2[srB + tid];
            obB = Ew2[(size_t)vB * 64 + l6] - lse_em2[sB + l6];
            float vraw[16];
            #pragma unroll
            for (int kk = 0; kk < 16; ++kk)
                vraw[kk] = V2[(size_t)(srB + q * 16 + kk) * SPWW + l6];
            __syncthreads();
            float mlocB = -3e38f;
            #pragma unroll
            for (int kk = 0; kk < 16; ++kk) {
                vb[kk] = vraw[kk] + rtB_l[q * 16 + kk];
                mlocB = fmaxf(mlocB, vb[kk]);
            }
            part[1][q][l6] = mlocB;
        } else {
            const float* Bf = Lin + ((size_t)(b * (4 * nodes) + in0 + s)) * 4096;
            float mlocB = -3e38f;
            #pragma unroll
            for (int kk = 0; kk < 16; ++kk) {
                float v = Bf[(q * 16 + kk) * 64 + l6];
                vb[kk] = v; mlocB = fmaxf(mlocB, v);
            }
            part[1][q][l6] = mlocB;
        }
        __syncthreads();

        if (tid < 64) {
            float mf = fmaxf(fmaxf(part[0][0][tid], part[0][1][tid]),
                             fmaxf(part[0][2][tid], part[0][3][tid]));
            mAf[tid] = mf;
            mA2[tid] = mf + ((LEAF && s == 1) ? rowA : 0.f);
        } else if (tid < 128) {
            int j = tid & 63;
            float mf = fmaxf(fmaxf(part[1][0][j], part[1][1][j]),
                             fmaxf(part[1][2][j], part[1][3][j]));
            mBf[j] = mf;
            mB2[j] = mf + obB;
        }
        __syncthreads();

        {
            float ma = mAf[l6];
            u16 pk[16];
            #pragma unroll
            for (int e = 0; e < 16; ++e) pk[e] = f2bf(ex2(va[e] - ma));
            uint4* srcv = (uint4*)pk;
            int base = l6 * 128;
            int s0 = 2 * q, s1 = 2 * q + 1, sw = (l6 & 7);
            *(uint4*)&Ps[base + ((s0 ^ sw) << 4)] = srcv[0];
            *(uint4*)&Ps[base + ((s1 ^ sw) << 4)] = srcv[1];
            float mb = mBf[l6];
            #pragma unroll
            for (int e = 0; e < 16; ++e) pk[e] = f2bf(ex2(vb[e] - mb));
            *(uint4*)&Qs[base + ((s0 ^ sw) << 4)] = srcv[0];
            *(uint4*)&Qs[base + ((s1 ^ sw) << 4)] = srcv[1];
        }
        __syncthreads();

        int w = q, lr = l6 & 15, lg = l6 >> 4;
        int brow = w * 16 + lr;
        short8 bfr[2];
        #pragma unroll
        for (int ks = 0; ks < 2; ++ks)
            bfr[ks] = *(const short8*)(Qs + brow * 128 + (((ks * 4 + lg) << 4) ^ ((brow & 7) << 4)));
        bool last = (s == nm - 1);
        float* Co = Lout + ((size_t)(b * nodes + p)) * 4096;
        #pragma unroll
        for (int rm = 0; rm < 4; ++rm) {
            f32x4 acc = {0.f, 0.f, 0.f, 0.f};
            int ar = rm * 16 + lr;
            #pragma unroll
            for (int ks = 0; ks < 2; ++ks) {
                short8 af = *(const short8*)(Ps + ar * 128 + (((ks * 4 + lg) << 4) ^ ((ar & 7) << 4)));
                acc = __builtin_amdgcn_mfma_f32_16x16x32_bf16(af, bfr[ks], acc, 0, 0, 0);
            }
            #pragma unroll
            for (int e = 0; e < 4; ++e) {
                int ii = rm * 16 + lg * 4 + e;
                int jj = w * 16 + lr;
                float cv = mA2[ii] + mB2[jj] + lg2(fmaxf(acc[e], 1e-33f));
                if (last) Co[ii * 64 + jj] = cv;
                else      Rb[ii][jj] = cv;
            }
        }
        if (!last) {
            __syncthreads();
            #pragma unroll
            for (int jj = 0; jj < 16; ++jj)
                va[jj] = Rb[l6][q * 16 + jj];
        }
    }
}

// ================= fused last tree level + start-lse + final lse ==================
__global__ __launch_bounds__(256) void fhmm_tree_final(
    const float* __restrict__ Lin,
    const float* __restrict__ startv, const float* __restrict__ Ew2,
    const float* __restrict__ lse_em2,
    const int* __restrict__ text, const int* __restrict__ w2s,
    float* __restrict__ out)
{
    int b = blockIdx.x;
    int tid = threadIdx.x;
    int l6 = tid & 63, q = tid >> 6;

    __shared__ float Rb[64][65];
    __shared__ char Ps[8192], Qs[8192];
    __shared__ float mA2[64], mB2[64], mAf[64], mBf[64];
    __shared__ float part[2][4][64];
    __shared__ float a0[64];
    __shared__ float rm_[4], rs_[4];
    __shared__ float lse_start_s;

    // ---- global lse2 of raw start logits (pb cancels in log_softmax) ----
    {
        float m = -3e38f, s = 0.f;
        for (int i = tid; i < CST; i += 256) {
            float v = startv[i] * LOG2E;
            float mn = fmaxf(m, v);
            s = s * ex2(m - mn) + ex2(v - mn);
            m = mn;
        }
        #pragma unroll
        for (int d = 32; d; d >>= 1) {
            float m2 = __shfl_xor(m, d), sx = __shfl_xor(s, d);
            float mn = fmaxf(m, m2);
            s = s * ex2(m - mn) + sx * ex2(m2 - mn); m = mn;
        }
        if ((tid & 63) == 0) { rm_[tid >> 6] = m; rs_[tid >> 6] = s; }
        __syncthreads();
        if (tid == 0) {
            float M_ = rm_[0], S_ = rs_[0];
            #pragma unroll
            for (int qq = 1; qq < 4; ++qq) {
                float mn = fmaxf(M_, rm_[qq]);
                S_ = S_ * ex2(M_ - mn) + rs_[qq] * ex2(rm_[qq] - mn); M_ = mn;
            }
            lse_start_s = M_ + lg2(S_);
        }
        __syncthreads();
    }

    float va[16];
    {
        const float* Af = Lin + ((size_t)(b * 4)) * 4096;
        #pragma unroll
        for (int jj = 0; jj < 16; ++jj)
            va[jj] = Af[l6 * 64 + q * 16 + jj];
    }

    for (int s = 1; s < 4; ++s) {
        float mloc = -3e38f;
        #pragma unroll
        for (int jj = 0; jj < 16; ++jj) mloc = fmaxf(mloc, va[jj]);
        part[0][q][l6] = mloc;

        const float* Bf = Lin + ((size_t)(b * 4 + s)) * 4096;
        float vb[16];
        float mlocB = -3e38f;
        #pragma unroll
        for (int kk = 0; kk < 16; ++kk) {
            float v = Bf[(q * 16 + kk) * 64 + l6];
            vb[kk] = v; mlocB = fmaxf(mlocB, v);
        }
        part[1][q][l6] = mlocB;
        __syncthreads();

        if (tid < 64) {
            float mf = fmaxf(fmaxf(part[0][0][tid], part[0][1][tid]),
                             fmaxf(part[0][2][tid], part[0][3][tid]));
            mAf[tid] = mf; mA2[tid] = mf;
        } else if (tid < 128) {
            int j = tid & 63;
            float mf = fmaxf(fmaxf(part[1][0][j], part[1][1][j]),
                             fmaxf(part[1][2][j], part[1][3][j]));
            mBf[j] = mf; mB2[j] = mf;
        }
        __syncthreads();

        {
            float ma = mAf[l6];
            u16 pk[16];
            #pragma unroll
            for (int e = 0; e < 16; ++e) pk[e] = f2bf(ex2(va[e] - ma));
            uint4* srcv = (uint4*)pk;
            int base = l6 * 128;
            int s0 = 2 * q, s1 = 2 * q + 1, sw = (l6 & 7);
            *(uint4*)&Ps[base + ((s0 ^ sw) << 4)] = srcv[0];
            *(uint4*)&Ps[base + ((s1 ^ sw) << 4)] = srcv[1];
            float mb = mBf[l6];
            #pragma unroll
            for (int e = 0; e < 16; ++e) pk[e] = f2bf(ex2(vb[e] - mb));
            *(uint4*)&Qs[base + ((s0 ^ sw) << 4)] = srcv[0];
            *(uint4*)&Qs[base + ((s1 ^ sw) << 4)] = srcv[1];
        }
        __syncthreads();

        int w = q, lr = l6 & 15, lg = l6 >> 4;
        int brow = w * 16 + lr;
        short8 bfr[2];
        #pragma unroll
        for (int ks = 0; ks < 2; ++ks)
            bfr[ks] = *(const short8*)(Qs + brow * 128 + (((ks * 4 + lg) << 4) ^ ((brow & 7) << 4)));
        #pragma unroll
        for (int rm = 0; rm < 4; ++rm) {
            f32x4 acc = {0.f, 0.f, 0.f, 0.f};
            int ar = rm * 16 + lr;
            #pragma unroll
            for (int ks = 0; ks < 2; ++ks) {
                short8 af = *(const short8*)(Ps + ar * 128 + (((ks * 4 + lg) << 4) ^ ((ar & 7) << 4)));
                acc = __builtin_amdgcn_mfma_f32_16x16x32_bf16(af, bfr[ks], acc, 0, 0, 0);
            }
            #pragma unroll
            for (int e = 0; e < 4; ++e) {
                int ii = rm * 16 + lg * 4 + e;
                int jj = w * 16 + lr;
                Rb[ii][jj] = mA2[ii] + mB2[jj] + lg2(fmaxf(acc[e], 1e-33f));
            }
        }
        __syncthreads();
        if (s < 3) {
            #pragma unroll
            for (int jj = 0; jj < 16; ++jj)
                va[jj] = Rb[l6][q * 16 + jj];
        }
    }

    // a0 (raw start, normalization applied as scalar at the end) and final lse
    if (tid < 64) {
        int v0 = text[b * TTT];
        int s0 = w2s[v0 * SPWW];
        a0[tid] = startv[s0 + tid] * LOG2E + Ew2[(size_t)v0 * 64 + tid] - lse_em2[s0 + tid];
    }
    __syncthreads();
    float m = -3e38f, s = 0.f;
    for (int e = tid; e < 4096; e += 256) {
        float v = a0[e >> 6] + Rb[e >> 6][e & 63];
        float mn = fmaxf(m, v);
        s = s * ex2(m - mn) + ex2(v - mn);
        m = mn;
    }
    #pragma unroll
    for (int d = 32; d; d >>= 1) {
        float m2 = __shfl_xor(m, d), sx = __shfl_xor(s, d);
        float mn = fmaxf(m, m2);
        s = s * ex2(m - mn) + sx * ex2(m2 - mn); m = mn;
    }
    if ((tid & 63) == 0) { rm_[tid >> 6] = m; rs_[tid >> 6] = s; }
    __syncthreads();
    if (tid == 0) {
        float M_ = rm_[0], S_ = rs_[0];
        #pragma unroll
        for (int qq = 1; qq < 4; ++qq) {
            float mn = fmaxf(M_, rm_[qq]);
            S_ = S_ * ex2(M_ - mn) + rs_[qq] * ex2(rm_[qq] - mn); M_ = mn;
        }
        out[b] = (M_ + lg2(S_) - lse_start_s) * LN2;
    }
}

extern "C" void kernel_launch(void* const* d_in, const int* in_sizes, int n_in,
                              void* d_out, int out_size, void* d_ws, size_t ws_size,
                              hipStream_t stream) {
    const int* text        = (const int*)d_in[0];
    const int* w2s         = (const int*)d_in[1];
    const float* se1_start = (const float*)d_in[2];
    const float* se2_start = (const float*)d_in[3];
    const float* start_w1  = (const float*)d_in[4];
    const float* start_b1  = (const float*)d_in[5];
    const float* start_w2  = (const float*)d_in[6];
    const float* start_b2  = (const float*)d_in[7];
    const float* start_pw  = (const float*)d_in[8];
    const float* start_pb  = (const float*)d_in[9];
    const float* se1_state = (const float*)d_in[10];
    const float* se2_state = (const float*)d_in[11];
    const float* se1_next  = (const float*)d_in[12];
    const float* se2_next  = (const float*)d_in[13];
    const float* trans_w1  = (const float*)d_in[14];
    const float* trans_b1  = (const float*)d_in[15];
    const float* trans_w2  = (const float*)d_in[16];
    const float* trans_b2  = (const float*)d_in[17];
    const float* se1_pre   = (const float*)d_in[18];
    const float* se2_pre   = (const float*)d_in[19];
    const float* term_w1   = (const float*)d_in[20];
    const float* term_b1   = (const float*)d_in[21];
    const float* term_w2   = (const float*)d_in[22];
    const float* term_b2   = (const float*)d_in[23];
    const float* term_pw   = (const float*)d_in[24];
    const float* term_pb   = (const float*)d_in[25];
    float* out = (float*)d_out;

    char* wp = (char*)d_ws;
    auto alloc = [&](size_t bytes) {
        char* p = wp;
        wp += (bytes + 255) & ~(size_t)255;
        return (void*)p;
    };
    u16* h1a         = (u16*)alloc((size_t)CST * HH * 2);
    u16* h1b         = (u16*)alloc((size_t)CST * HH * 2);
    u16* h1c         = (u16*)alloc((size_t)CST * HH * 2);
    u16* h_state_bf  = (u16*)alloc((size_t)CST * HH * 2);
    u16* h_pre_bf    = (u16*)alloc((size_t)CST * HH * 2);
    u16* Wt          = (u16*)alloc((size_t)6 * HH * HH * 2);
    u16* pwT         = (u16*)alloc((size_t)VV * HH * 2);
    u16* e1n_bf      = (u16*)alloc((size_t)NCC * HH * 2);
    u16* e2n_bf      = (u16*)alloc((size_t)SPWW * HH * 2);
    float* U2        = (float*)alloc((size_t)CST * NCC * 4);
    float* V2        = (float*)alloc((size_t)CST * SPWW * 4);
    float* startv    = (float*)alloc(CST * 4);
    float* lse_trans = (float*)alloc(CST * 4);
    float* lse_em    = (float*)alloc(CST * 4);
    float* Ew        = (float*)alloc((size_t)VV * 64 * 4);
    int* counts      = (int*)alloc(NCC * 4);
    int* offsets     = (int*)alloc((NCC + 4) * 4);
    int* wlist       = (int*)alloc(VV * 4);
    float* LvA       = (float*)alloc((size_t)BBB * 64 * 4096 * 4);
    float* LvB       = (float*)alloc((size_t)BBB * 16 * 4096 * 4);
    float* LvC       = (float*)alloc((size_t)BBB * 4 * 4096 * 4);
    u16* dummyY      = (u16*)alloc(256 * 2);

    // ---- mega setup ----
    SetupA sa;
    sa.Ws[0] = start_w1; sa.Ws[1] = start_w2; sa.Ws[2] = trans_w1;
    sa.Ws[3] = trans_w2; sa.Ws[4] = term_w1;  sa.Ws[5] = term_w2;
    sa.Wt = Wt; sa.pw = term_pw; sa.pwT = pwT;
    sa.e1n = se1_next; sa.e2n = se2_next; sa.e1nb = e1n_bf; sa.e2nb = e2n_bf;
    sa.w2s = w2s; sa.counts = counts; sa.offsets = offsets; sa.wlist = wlist;
    sa.startv = startv;
    hipLaunchKernelGGL(fhmm_setup, dim3(885), 256, 0, stream, sa);

    // ---- batched MLP layer 1 (emb on the fly) ----
    MlpA m1;
    m1.X[0] = m1.X[1] = m1.X[2] = nullptr;
    m1.se1[0] = se1_start; m1.se1[1] = se1_state; m1.se1[2] = se1_pre;
    m1.se2[0] = se2_start; m1.se2[1] = se2_state; m1.se2[2] = se2_pre;
    m1.Wth[0] = Wt + 0 * HH * HH; m1.Wth[1] = Wt + 2 * HH * HH; m1.Wth[2] = Wt + 4 * HH * HH;
    m1.bias[0] = start_b1; m1.bias[1] = trans_b1; m1.bias[2] = term_b1;
    m1.Y[0] = h1a; m1.Y[1] = h1b; m1.Y[2] = h1c;
    m1.oscale[0] = m1.oscale[1] = m1.oscale[2] = 1.0f;
    m1.pw = start_pw; m1.startv = startv;
    hipLaunchKernelGGL((fhmm_mlp_batch<0>), dim3(128, 4, 3), 256, 0, stream, m1);

    // ---- batched MLP layer 2 (residual on the fly; head0 -> startv atomics) ----
    MlpA m2 = m1;
    m2.X[0] = h1a; m2.X[1] = h1b; m2.X[2] = h1c;
    m2.Wth[0] = Wt + 1 * HH * HH; m2.Wth[1] = Wt + 3 * HH * HH; m2.Wth[2] = Wt + 5 * HH * HH;
    m2.bias[0] = start_b2; m2.bias[1] = trans_b2; m2.bias[2] = term_b2;
    m2.Y[0] = dummyY; m2.Y[1] = h_state_bf; m2.Y[2] = h_pre_bf;
    m2.oscale[0] = 1.0f; m2.oscale[1] = LOG2E; m2.oscale[2] = 1.0f;
    hipLaunchKernelGGL((fhmm_mlp_batch<1>), dim3(128, 4, 3), 256, 0, stream, m2);

    // ---- U/V GEMMs + fused row-lse ----
    hipLaunchKernelGGL(fhmm_gemm_uv_lse, dim3(128), 256, 0, stream,
                       h_state_bf, e1n_bf, e2n_bf, U2, V2, lse_trans);

    // ---- emission (Ew2 + fused lse_em2) ----
    hipLaunchKernelGGL(fhmm_ew_mfma, dim3(NCC), 256, 0, stream,
                       h_pre_bf, pwT, term_pb, wlist, counts, offsets, Ew, lse_em);

    // ---- 4-ary tree ----
    hipLaunchKernelGGL((fhmm_combine4<1>), dim3(64, BBB), 256, 0, stream,
                       U2, V2, Ew, lse_em, lse_trans, text, w2s,
                       (const float*)nullptr, LvA);
    hipLaunchKernelGGL((fhmm_combine4<0>), dim3(16, BBB), 256, 0, stream,
                       (const float*)nullptr, (const float*)nullptr,
                       (const float*)nullptr, (const float*)nullptr,
                       (const float*)nullptr, (const int*)nullptr,
                       (const int*)nullptr, LvA, LvB);
    hipLaunchKernelGGL((fhmm_combine4<0>), dim3(4, BBB), 256, 0, stream,
                       (const float*)nullptr, (const float*)nullptr,
                       (const float*)nullptr, (const float*)nullptr,
                       (const float*)nullptr, (const int*)nullptr,
                       (const int*)nullptr, LvB, LvC);

    // ---- last tree level + start-lse + final lse ----
    hipLaunchKernelGGL(fhmm_tree_final, dim3(BBB), 256, 0, stream,
                       LvC, startv, Ew, lse_em, text, w2s, out);
}

// Round 12
// 115.746 us; speedup vs baseline: 1.0933x; 1.0933x over previous
//
#include <hip/hip_runtime.h>
#include <hip/hip_bf16.h>
#include <math.h>

#define HH 256
#define NCC 128
#define SPWW 64
#define CST 8192
#define VV 10000
#define BBB 16
#define TTT 256
#define LOG2E 1.4426950408889634f
#define LN2 0.6931471805599453f

typedef __attribute__((ext_vector_type(8))) short short8;
typedef __attribute__((ext_vector_type(4))) float f32x4;
typedef unsigned short u16;

__device__ inline float bf2f(u16 u) {
    union { unsigned int i; float f; } v; v.i = ((unsigned int)u) << 16; return v.f;
}
__device__ inline u16 f2bf(float f) {
    __hip_bfloat16 h = __float2bfloat16(f);
    return *reinterpret_cast<u16*>(&h);
}
__device__ inline float ex2(float x) { return __builtin_amdgcn_exp2f(x); }
__device__ inline float lg2(float x) { return __builtin_amdgcn_logf(x); }   // v_log_f32 = log2

// ================= mega-setup: wtrans(96) + pwtrans(628) + embnext(128) + zero-startv(32) + class-bin(128) =================
// wlist is FIXED-SLOT: wlist[c*256 + i], i < counts[c]; order within class irrelevant.
struct SetupA {
    const float* Ws[6]; u16* Wt;
    const float* pw; u16* pwT;
    const float* e1n; const float* e2n; u16* e1nb; u16* e2nb;
    const int* w2s; int* counts; int* wlist;
    float* startv;
};
__global__ __launch_bounds__(256) void fhmm_setup(SetupA a)
{
    __shared__ float t[64][65];
    int blk = blockIdx.x, tid = threadIdx.x;
    if (blk < 96) {
        int z = blk >> 4, r = blk & 15;
        int k0 = (r & 3) * 64, n0 = (r >> 2) * 64;
        const float* W = a.Ws[z];
        u16* dst = a.Wt + (size_t)z * HH * HH;
        #pragma unroll
        for (int i = 0; i < 16; ++i) {
            int idx = tid + i * 256; int rr = idx >> 6, c = idx & 63;
            t[rr][c] = W[(k0 + rr) * HH + n0 + c];
        }
        __syncthreads();
        #pragma unroll
        for (int i = 0; i < 16; ++i) {
            int idx = tid + i * 256; int rr = idx >> 6, c = idx & 63;
            dst[(n0 + rr) * HH + k0 + c] = f2bf(t[c][rr]);
        }
    } else if (blk < 724) {
        int idx = blk - 96;
        int v0 = (idx % 157) * 64, k0 = (idx / 157) * 64;
        #pragma unroll
        for (int i = 0; i < 16; ++i) {
            int id2 = tid + i * 256; int rr = id2 >> 6, c = id2 & 63;   // rr:k, c:v
            int v = v0 + c;
            t[rr][c] = (v < VV) ? a.pw[(size_t)(k0 + rr) * VV + v] : 0.f;
        }
        __syncthreads();
        #pragma unroll
        for (int i = 0; i < 16; ++i) {
            int id2 = tid + i * 256; int rr = id2 >> 6, c = id2 & 63;   // rr:v, c:k
            int v = v0 + rr;
            if (v < VV) a.pwT[(size_t)v * HH + k0 + c] = f2bf(t[c][rr]);
        }
    } else if (blk < 852) {
        int idx = (blk - 724) * 256 + tid;
        if (idx < NCC * HH) a.e1nb[idx] = f2bf(a.e1n[idx]);
        if (idx < SPWW * HH) a.e2nb[idx] = f2bf(a.e2n[idx]);
    } else if (blk < 884) {
        int idx = (blk - 852) * 256 + tid;
        if (idx < CST) a.startv[idx] = 0.f;
    } else {
        // one block per class: append matching words to fixed-slot list
        int c = blk - 884;
        __shared__ int cnt;
        if (tid == 0) cnt = 0;
        __syncthreads();
        for (int v = tid; v < VV; v += 256) {
            if ((a.w2s[v * SPWW] >> 6) == c) {
                int pos = atomicAdd(&cnt, 1);
                a.wlist[c * 256 + pos] = v;
            }
        }
        __syncthreads();
        if (tid == 0) a.counts[c] = cnt;
    }
}

// ================= batched MFMA MLP (3 heads per launch) =================
// LAYER 0: X = bf16(se1+se2) computed on the fly, Y = relu(X@W+b)
// LAYER 1: X = X[h] (bf16), Y = (relu(X@W+b) + (se1+se2)) * oscale;
//          head 0: Y not stored; raw f32 output dotted with pw -> atomicAdd startv.
struct MlpA {
    const u16* X[3];
    const float* se1[3]; const float* se2[3];
    const u16* Wth[3];
    const float* bias[3];
    u16* Y[3];
    float oscale[3];
    const float* pw;
    float* startv;
};
template<int LAYER>
__global__ __launch_bounds__(256) void fhmm_mlp_batch(MlpA a)
{
    int hd = blockIdx.z;
    int m0 = blockIdx.x * 64, n0 = blockIdx.y * 64;
    __shared__ char Xs[32768];
    __shared__ char Ws[32768];
    int tid = threadIdx.x, w = tid >> 6, lane = tid & 63, lr = lane & 15, lg = lane >> 4;
    const char* wsrc = (const char*)(a.Wth[hd] + (size_t)n0 * HH);
    if (LAYER == 0) {
        const float* s1 = a.se1[hd];
        const float* s2 = a.se2[hd];
        #pragma unroll
        for (int i = 0; i < 8; ++i) {
            int cc = i * 256 + tid; int row = cc >> 5, tt = cc & 31;
            int gm = m0 + row, k = tt * 8;
            const float* p1 = s1 + (gm >> 6) * HH + k;
            const float* p2 = s2 + (gm & 63) * HH + k;
            u16 pk[8];
            #pragma unroll
            for (int e = 0; e < 8; ++e) pk[e] = f2bf(p1[e] + p2[e]);
            int dst = row * 512 + ((tt ^ (row & 7)) << 4);
            *(uint4*)&Xs[dst] = *(uint4*)pk;
            *(uint4*)&Ws[dst] = *(const uint4*)(wsrc + cc * 16);
        }
    } else {
        const char* xsrc = (const char*)(a.X[hd] + (size_t)m0 * HH);
        #pragma unroll
        for (int i = 0; i < 8; ++i) {
            int cc = i * 256 + tid; int row = cc >> 5, tt = cc & 31;
            int dst = row * 512 + ((tt ^ (row & 7)) << 4);
            *(uint4*)&Xs[dst] = *(const uint4*)(xsrc + cc * 16);
            *(uint4*)&Ws[dst] = *(const uint4*)(wsrc + cc * 16);
        }
    }
    __syncthreads();
    short8 bfr[8];
    int brow = w * 16 + lr, bb = brow * 512, bsw = (brow & 7) << 4;
    #pragma unroll
    for (int ks = 0; ks < 8; ++ks)
        bfr[ks] = *(const short8*)(Ws + bb + (((ks * 4 + lg) << 4) ^ bsw));
    int cb = w * 16 + lg * 4;
    f32x4 bv = *(const f32x4*)(a.bias[hd] + n0 + cb);
    float osc = a.oscale[hd];
    u16* Yp = a.Y[hd];
    #pragma unroll
    for (int rm = 0; rm < 4; ++rm) {
        f32x4 acc = {0.f, 0.f, 0.f, 0.f};
        int ar = rm * 16 + lr, ab = ar * 512, asw = (ar & 7) << 4;
        #pragma unroll
        for (int ks = 0; ks < 8; ++ks) {
            short8 af = *(const short8*)(Xs + ab + (((ks * 4 + lg) << 4) ^ asw));
            acc = __builtin_amdgcn_mfma_f32_16x16x32_bf16(bfr[ks], af, acc, 0, 0, 0);
        }
        int gm = m0 + rm * 16 + lr;
        if (LAYER == 1) {
            const float* r1 = a.se1[hd] + (gm >> 6) * HH + n0 + cb;
            const float* r2 = a.se2[hd] + (gm & 63) * HH + n0 + cb;
            float vals[4];
            #pragma unroll
            for (int e = 0; e < 4; ++e)
                vals[e] = fmaxf(acc[e] + bv[e], 0.f) + r1[e] + r2[e];
            if (hd == 0) {
                const float* pwc = a.pw + n0 + cb;
                float dotp = vals[0] * pwc[0] + vals[1] * pwc[1]
                           + vals[2] * pwc[2] + vals[3] * pwc[3];
                dotp += __shfl_xor(dotp, 16);
                dotp += __shfl_xor(dotp, 32);
                if (lg == 0) atomicAdd(&a.startv[gm], dotp);
            } else {
                ushort4 o;
                #pragma unroll
                for (int e = 0; e < 4; ++e) ((u16*)&o)[e] = f2bf(vals[e] * osc);
                *(ushort4*)(Yp + (size_t)gm * HH + n0 + cb) = o;
            }
        } else {
            ushort4 o;
            #pragma unroll
            for (int e = 0; e < 4; ++e)
                ((u16*)&o)[e] = f2bf(fmaxf(acc[e] + bv[e], 0.f));
            *(ushort4*)(Yp + (size_t)gm * HH + n0 + cb) = o;
        }
    }
}

// ================= U/V GEMM + fused row-lse: one block = 64 rows, all 3 B-tiles =================
__global__ __launch_bounds__(256) void fhmm_gemm_uv_lse(
    const u16* __restrict__ Abf, const u16* __restrict__ e1n,
    const u16* __restrict__ e2n, float* __restrict__ U2, float* __restrict__ V2,
    float* __restrict__ lse_trans2)
{
    int m0 = blockIdx.x * 64;
    __shared__ char Xs[32768];
    __shared__ char Ws[32768];
    __shared__ float lmU[4][64], lsU[4][64], lmV[4][64], lsV[4][64];
    int tid = threadIdx.x, w = tid >> 6, lane = tid & 63, lr = lane & 15, lg = lane >> 4;
    const char* xsrc = (const char*)(Abf + (size_t)m0 * HH);
    #pragma unroll
    for (int i = 0; i < 8; ++i) {
        int cc = i * 256 + tid; int row = cc >> 5, tt = cc & 31;
        int dst = row * 512 + ((tt ^ (row & 7)) << 4);
        *(uint4*)&Xs[dst] = *(const uint4*)(xsrc + cc * 16);
    }

    float mU[4], sU[4], mV[4], sV[4];
    #pragma unroll
    for (int rm = 0; rm < 4; ++rm) { mU[rm] = -3e38f; sU[rm] = 0.f; mV[rm] = -3e38f; sV[rm] = 0.f; }

    int cb = w * 16 + lg * 4;
    for (int y = 0; y < 3; ++y) {
        const char* wsrc = (y < 2) ? (const char*)(e1n + (size_t)y * 64 * HH)
                                   : (const char*)e2n;
        __syncthreads();
        #pragma unroll
        for (int i = 0; i < 8; ++i) {
            int cc = i * 256 + tid; int row = cc >> 5, tt = cc & 31;
            int dst = row * 512 + ((tt ^ (row & 7)) << 4);
            *(uint4*)&Ws[dst] = *(const uint4*)(wsrc + cc * 16);
        }
        __syncthreads();
        short8 bfr[8];
        int brow = w * 16 + lr, bb = brow * 512, bsw = (brow & 7) << 4;
        #pragma unroll
        for (int ks = 0; ks < 8; ++ks)
            bfr[ks] = *(const short8*)(Ws + bb + (((ks * 4 + lg) << 4) ^ bsw));
        #pragma unroll
        for (int rm = 0; rm < 4; ++rm) {
            f32x4 acc = {0.f, 0.f, 0.f, 0.f};
            int ar = rm * 16 + lr, ab = ar * 512, asw = (ar & 7) << 4;
            #pragma unroll
            for (int ks = 0; ks < 8; ++ks) {
                short8 af = *(const short8*)(Xs + ab + (((ks * 4 + lg) << 4) ^ asw));
                acc = __builtin_amdgcn_mfma_f32_16x16x32_bf16(bfr[ks], af, acc, 0, 0, 0);
            }
            int gm = m0 + rm * 16 + lr;
            float lm = fmaxf(fmaxf(acc[0], acc[1]), fmaxf(acc[2], acc[3]));
            if (y < 2) {
                *(f32x4*)(U2 + (size_t)gm * NCC + y * 64 + cb) = acc;
                float mn = fmaxf(mU[rm], lm);
                sU[rm] = sU[rm] * ex2(mU[rm] - mn)
                       + ex2(acc[0] - mn) + ex2(acc[1] - mn)
                       + ex2(acc[2] - mn) + ex2(acc[3] - mn);
                mU[rm] = mn;
            } else {
                *(f32x4*)(V2 + (size_t)gm * SPWW + cb) = acc;
                float mn = fmaxf(mV[rm], lm);
                sV[rm] = sV[rm] * ex2(mV[rm] - mn)
                       + ex2(acc[0] - mn) + ex2(acc[1] - mn)
                       + ex2(acc[2] - mn) + ex2(acc[3] - mn);
                mV[rm] = mn;
            }
        }
    }

    #pragma unroll
    for (int rm = 0; rm < 4; ++rm) {
        #pragma unroll
        for (int d = 16; d < 64; d <<= 1) {
            float m2 = __shfl_xor(mU[rm], d), sx = __shfl_xor(sU[rm], d);
            float mn = fmaxf(mU[rm], m2);
            sU[rm] = sU[rm] * ex2(mU[rm] - mn) + sx * ex2(m2 - mn); mU[rm] = mn;
            m2 = __shfl_xor(mV[rm], d); sx = __shfl_xor(sV[rm], d);
            mn = fmaxf(mV[rm], m2);
            sV[rm] = sV[rm] * ex2(mV[rm] - mn) + sx * ex2(m2 - mn); mV[rm] = mn;
        }
    }
    __syncthreads();
    if (lg == 0) {
        #pragma unroll
        for (int rm = 0; rm < 4; ++rm) {
            lmU[w][rm * 16 + lr] = mU[rm]; lsU[w][rm * 16 + lr] = sU[rm];
            lmV[w][rm * 16 + lr] = mV[rm]; lsV[w][rm * 16 + lr] = sV[rm];
        }
    }
    __syncthreads();
    if (tid < 64) {
        float MU = lmU[0][tid], SU = lsU[0][tid];
        float MV = lmV[0][tid], SV = lsV[0][tid];
        #pragma unroll
        for (int q = 1; q < 4; ++q) {
            float m2 = lmU[q][tid], sx = lsU[q][tid];
            float mn = fmaxf(MU, m2);
            SU = SU * ex2(MU - mn) + sx * ex2(m2 - mn); MU = mn;
            m2 = lmV[q][tid]; sx = lsV[q][tid];
            mn = fmaxf(MV, m2);
            SV = SV * ex2(MV - mn) + sx * ex2(m2 - mn); MV = mn;
        }
        lse_trans2[m0 + tid] = (MU + lg2(SU)) + (MV + lg2(SV));
    }
}

// ---------------- per-class emission GEMM + fused per-state lse (base-2) ----------------
// wlist fixed-slot: words of class c at wlist[c*256 .. c*256+counts[c])
__global__ __launch_bounds__(256) void fhmm_ew_mfma(
    const u16* __restrict__ hpre_bf, const u16* __restrict__ pwT,
    const float* __restrict__ pb, const int* __restrict__ wlist,
    const int* __restrict__ counts,
    float* __restrict__ Ew2, float* __restrict__ lse_em2)
{
    int c = blockIdx.x;
    int cnt = counts[c], off = c * 256;
    __shared__ char Hs[32768];
    __shared__ float emM[4][64], emS[4][64];
    int tid = threadIdx.x, w = tid >> 6, lane = tid & 63, lr = lane & 15, lg = lane >> 4;
    const char* src = (const char*)(hpre_bf + (size_t)c * 64 * HH);
    #pragma unroll
    for (int i = 0; i < 8; ++i) {
        int cc = i * 256 + tid; int row = cc >> 5, tt = cc & 31;
        *(uint4*)&Hs[row * 512 + ((tt ^ (row & 7)) << 4)] = *(const uint4*)(src + cc * 16);
    }
    __syncthreads();

    float em_m[4][4], em_s[4][4];
    #pragma unroll
    for (int rm = 0; rm < 4; ++rm)
        #pragma unroll
        for (int e = 0; e < 4; ++e) { em_m[rm][e] = -3e38f; em_s[rm][e] = 0.f; }

    for (int ch = 0; ch * 64 < cnt; ++ch) {
        int widx = ch * 64 + w * 16 + lr;
        bool valid = widx < cnt;
        int v = valid ? wlist[off + widx] : 0;
        short8 bw[8];
        short8 bz = {0, 0, 0, 0, 0, 0, 0, 0};
        #pragma unroll
        for (int ks = 0; ks < 8; ++ks)
            bw[ks] = valid ? *(const short8*)(pwT + (size_t)v * HH + ks * 32 + lg * 8) : bz;
        float pbv = valid ? pb[v] : 0.f;
        #pragma unroll
        for (int rm = 0; rm < 4; ++rm) {
            f32x4 acc = {0.f, 0.f, 0.f, 0.f};
            int ar = rm * 16 + lr, ab = ar * 512, asw = (ar & 7) << 4;
            #pragma unroll
            for (int ks = 0; ks < 8; ++ks) {
                short8 ah = *(const short8*)(Hs + ab + (((ks * 4 + lg) << 4) ^ asw));
                acc = __builtin_amdgcn_mfma_f32_16x16x32_bf16(ah, bw[ks], acc, 0, 0, 0);
            }
            f32x4 o;
            #pragma unroll
            for (int e = 0; e < 4; ++e) o[e] = (acc[e] + pbv) * LOG2E;
            if (valid)
                *(f32x4*)(Ew2 + (size_t)v * 64 + rm * 16 + lg * 4) = o;
            #pragma unroll
            for (int e = 0; e < 4; ++e) {
                if (valid) {
                    float mn = fmaxf(em_m[rm][e], o[e]);
                    em_s[rm][e] = em_s[rm][e] * ex2(em_m[rm][e] - mn) + ex2(o[e] - mn);
                    em_m[rm][e] = mn;
                }
            }
        }
    }

    #pragma unroll
    for (int rm = 0; rm < 4; ++rm)
        #pragma unroll
        for (int e = 0; e < 4; ++e) {
            float mm = em_m[rm][e], ss = em_s[rm][e];
            #pragma unroll
            for (int d = 1; d < 16; d <<= 1) {
                float m2 = __shfl_xor(mm, d);
                float s2 = __shfl_xor(ss, d);
                float mn = fmaxf(mm, m2);
                ss = ss * ex2(mm - mn) + s2 * ex2(m2 - mn);
                mm = mn;
            }
            em_m[rm][e] = mm; em_s[rm][e] = ss;
        }
    if (lr == 0) {
        #pragma unroll
        for (int rm = 0; rm < 4; ++rm)
            #pragma unroll
            for (int e = 0; e < 4; ++e) {
                emM[w][rm * 16 + lg * 4 + e] = em_m[rm][e];
                emS[w][rm * 16 + lg * 4 + e] = em_s[rm][e];
            }
    }
    __syncthreads();
    if (tid < 64) {
        float M = emM[0][tid], S = emS[0][tid];
        #pragma unroll
        for (int q2 = 1; q2 < 4; ++q2) {
            float m2 = emM[q2][tid], s2 = emS[q2][tid];
            float mn = fmaxf(M, m2);
            S = S * ex2(M - mn) + s2 * ex2(m2 - mn); M = mn;
        }
        lse_em2[c * 64 + tid] = M + lg2(fmaxf(S, 1e-33f));
    }
}

// ================= 4-ARY TREE COMBINE in lse2 semiring (obs computed inline) ==================
// LEAF=1: M_t[i][j] = U2[sr+i][c_t] - lse2[sr+i] + V2[sr+i][j] + Ew2[v_t*64+j] - lse_em2[64c_t+j]
template<int LEAF>
__global__ __launch_bounds__(256) void fhmm_combine4(
    const float* __restrict__ U2, const float* __restrict__ V2,
    const float* __restrict__ Ew2, const float* __restrict__ lse_em2,
    const float* __restrict__ lse2,
    const int* __restrict__ text, const int* __restrict__ w2s,
    const float* __restrict__ Lin, float* __restrict__ Lout)
{
    int p = blockIdx.x, b = blockIdx.y;
    int nodes = gridDim.x;
    int tid = threadIdx.x;
    int l6 = tid & 63, q = tid >> 6;

    __shared__ float Rb[64][65];
    __shared__ char Ps[8192], Qs[8192];
    __shared__ float mA2[64], mB2[64], mAf[64], mBf[64];
    __shared__ float part[2][4][64];
    __shared__ float rtB_l[64];

    int nm = LEAF ? ((p == 63) ? 3 : 4) : 4;
    int t0 = 4 * p + 1;
    int in0 = 4 * p;

    float va[16];
    float rowA = 0.f;

    if (LEAF) {
        int vprev = text[b * TTT + (t0 - 1)];
        int vA = text[b * TTT + t0];
        int srA = w2s[vprev * SPWW];
        int sA = w2s[vA * SPWW];          // = 64*cA
        int cA = sA >> 6;
        rowA = U2[(size_t)(srA + l6) * NCC + cA] - lse2[srA + l6];
        const float* vrow = V2 + (size_t)(srA + l6) * SPWW;
        const float* ewA = Ew2 + (size_t)vA * 64;
        const float* leA = lse_em2 + sA;
        #pragma unroll
        for (int jj = 0; jj < 16; ++jj) {
            int j = q * 16 + jj;
            va[jj] = vrow[j] + ewA[j] - leA[j];
        }
    } else {
        const float* Af = Lin + ((size_t)(b * (4 * nodes) + in0)) * 4096;
        #pragma unroll
        for (int jj = 0; jj < 16; ++jj)
            va[jj] = Af[l6 * 64 + q * 16 + jj];
    }

    for (int s = 1; s < nm; ++s) {
        float mloc = -3e38f;
        #pragma unroll
        for (int jj = 0; jj < 16; ++jj) mloc = fmaxf(mloc, va[jj]);
        part[0][q][l6] = mloc;

        float vb[16], obB = 0.f;
        if (LEAF) {
            int tB = t0 + s;
            int vBp = text[b * TTT + (tB - 1)];
            int vB = text[b * TTT + tB];
            int srB = w2s[vBp * SPWW];
            int sB = w2s[vB * SPWW];
            int cB = sB >> 6;
            if (tid < 64)
                rtB_l[tid] = U2[(size_t)(srB + tid) * NCC + cB] - lse2[srB + tid];
            obB = Ew2[(size_t)vB * 64 + l6] - lse_em2[sB + l6];
            float vraw[16];
            #pragma unroll
            for (int kk = 0; kk < 16; ++kk)
                vraw[kk] = V2[(size_t)(srB + q * 16 + kk) * SPWW + l6];
            __syncthreads();
            float mlocB = -3e38f;
            #pragma unroll
            for (int kk = 0; kk < 16; ++kk) {
                vb[kk] = vraw[kk] + rtB_l[q * 16 + kk];
                mlocB = fmaxf(mlocB, vb[kk]);
            }
            part[1][q][l6] = mlocB;
        } else {
            const float* Bf = Lin + ((size_t)(b * (4 * nodes) + in0 + s)) * 4096;
            float mlocB = -3e38f;
            #pragma unroll
            for (int kk = 0; kk < 16; ++kk) {
                float v = Bf[(q * 16 + kk) * 64 + l6];
                vb[kk] = v; mlocB = fmaxf(mlocB, v);
            }
            part[1][q][l6] = mlocB;
        }
        __syncthreads();

        if (tid < 64) {
            float mf = fmaxf(fmaxf(part[0][0][tid], part[0][1][tid]),
                             fmaxf(part[0][2][tid], part[0][3][tid]));
            mAf[tid] = mf;
            mA2[tid] = mf + ((LEAF && s == 1) ? rowA : 0.f);
        } else if (tid < 128) {
            int j = tid & 63;
            float mf = fmaxf(fmaxf(part[1][0][j], part[1][1][j]),
                             fmaxf(part[1][2][j], part[1][3][j]));
            mBf[j] = mf;
            mB2[j] = mf + obB;
        }
        __syncthreads();

        {
            float ma = mAf[l6];
            u16 pk[16];
            #pragma unroll
            for (int e = 0; e < 16; ++e) pk[e] = f2bf(ex2(va[e] - ma));
            uint4* srcv = (uint4*)pk;
            int base = l6 * 128;
            int s0 = 2 * q, s1 = 2 * q + 1, sw = (l6 & 7);
            *(uint4*)&Ps[base + ((s0 ^ sw) << 4)] = srcv[0];
            *(uint4*)&Ps[base + ((s1 ^ sw) << 4)] = srcv[1];
            float mb = mBf[l6];
            #pragma unroll
            for (int e = 0; e < 16; ++e) pk[e] = f2bf(ex2(vb[e] - mb));
            *(uint4*)&Qs[base + ((s0 ^ sw) << 4)] = srcv[0];
            *(uint4*)&Qs[base + ((s1 ^ sw) << 4)] = srcv[1];
        }
        __syncthreads();

        int w = q, lr = l6 & 15, lg = l6 >> 4;
        int brow = w * 16 + lr;
        short8 bfr[2];
        #pragma unroll
        for (int ks = 0; ks < 2; ++ks)
            bfr[ks] = *(const short8*)(Qs + brow * 128 + (((ks * 4 + lg) << 4) ^ ((brow & 7) << 4)));
        bool last = (s == nm - 1);
        float* Co = Lout + ((size_t)(b * nodes + p)) * 4096;
        #pragma unroll
        for (int rm = 0; rm < 4; ++rm) {
            f32x4 acc = {0.f, 0.f, 0.f, 0.f};
            int ar = rm * 16 + lr;
            #pragma unroll
            for (int ks = 0; ks < 2; ++ks) {
                short8 af = *(const short8*)(Ps + ar * 128 + (((ks * 4 + lg) << 4) ^ ((ar & 7) << 4)));
                acc = __builtin_amdgcn_mfma_f32_16x16x32_bf16(af, bfr[ks], acc, 0, 0, 0);
            }
            #pragma unroll
            for (int e = 0; e < 4; ++e) {
                int ii = rm * 16 + lg * 4 + e;
                int jj = w * 16 + lr;
                float cv = mA2[ii] + mB2[jj] + lg2(fmaxf(acc[e], 1e-33f));
                if (last) Co[ii * 64 + jj] = cv;
                else      Rb[ii][jj] = cv;
            }
        }
        if (!last) {
            __syncthreads();
            #pragma unroll
            for (int jj = 0; jj < 16; ++jj)
                va[jj] = Rb[l6][q * 16 + jj];
        }
    }
}

// ================= fused last tree level + start-lse + final lse ==================
__global__ __launch_bounds__(256) void fhmm_tree_final(
    const float* __restrict__ Lin,
    const float* __restrict__ startv, const float* __restrict__ Ew2,
    const float* __restrict__ lse_em2,
    const int* __restrict__ text, const int* __restrict__ w2s,
    float* __restrict__ out)
{
    int b = blockIdx.x;
    int tid = threadIdx.x;
    int l6 = tid & 63, q = tid >> 6;

    __shared__ float Rb[64][65];
    __shared__ char Ps[8192], Qs[8192];
    __shared__ float mA2[64], mB2[64], mAf[64], mBf[64];
    __shared__ float part[2][4][64];
    __shared__ float a0[64];
    __shared__ float rm_[4], rs_[4];
    __shared__ float lse_start_s;

    // ---- global lse2 of raw start logits (pb cancels in log_softmax) ----
    {
        float m = -3e38f, s = 0.f;
        for (int i = tid; i < CST; i += 256) {
            float v = startv[i] * LOG2E;
            float mn = fmaxf(m, v);
            s = s * ex2(m - mn) + ex2(v - mn);
            m = mn;
        }
        #pragma unroll
        for (int d = 32; d; d >>= 1) {
            float m2 = __shfl_xor(m, d), sx = __shfl_xor(s, d);
            float mn = fmaxf(m, m2);
            s = s * ex2(m - mn) + sx * ex2(m2 - mn); m = mn;
        }
        if ((tid & 63) == 0) { rm_[tid >> 6] = m; rs_[tid >> 6] = s; }
        __syncthreads();
        if (tid == 0) {
            float M_ = rm_[0], S_ = rs_[0];
            #pragma unroll
            for (int qq = 1; qq < 4; ++qq) {
                float mn = fmaxf(M_, rm_[qq]);
                S_ = S_ * ex2(M_ - mn) + rs_[qq] * ex2(rm_[qq] - mn); M_ = mn;
            }
            lse_start_s = M_ + lg2(S_);
        }
        __syncthreads();
    }

    float va[16];
    {
        const float* Af = Lin + ((size_t)(b * 4)) * 4096;
        #pragma unroll
        for (int jj = 0; jj < 16; ++jj)
            va[jj] = Af[l6 * 64 + q * 16 + jj];
    }

    for (int s = 1; s < 4; ++s) {
        float mloc = -3e38f;
        #pragma unroll
        for (int jj = 0; jj < 16; ++jj) mloc = fmaxf(mloc, va[jj]);
        part[0][q][l6] = mloc;

        const float* Bf = Lin + ((size_t)(b * 4 + s)) * 4096;
        float vb[16];
        float mlocB = -3e38f;
        #pragma unroll
        for (int kk = 0; kk < 16; ++kk) {
            float v = Bf[(q * 16 + kk) * 64 + l6];
            vb[kk] = v; mlocB = fmaxf(mlocB, v);
        }
        part[1][q][l6] = mlocB;
        __syncthreads();

        if (tid < 64) {
            float mf = fmaxf(fmaxf(part[0][0][tid], part[0][1][tid]),
                             fmaxf(part[0][2][tid], part[0][3][tid]));
            mAf[tid] = mf; mA2[tid] = mf;
        } else if (tid < 128) {
            int j = tid & 63;
            float mf = fmaxf(fmaxf(part[1][0][j], part[1][1][j]),
                             fmaxf(part[1][2][j], part[1][3][j]));
            mBf[j] = mf; mB2[j] = mf;
        }
        __syncthreads();

        {
            float ma = mAf[l6];
            u16 pk[16];
            #pragma unroll
            for (int e = 0; e < 16; ++e) pk[e] = f2bf(ex2(va[e] - ma));
            uint4* srcv = (uint4*)pk;
            int base = l6 * 128;
            int s0 = 2 * q, s1 = 2 * q + 1, sw = (l6 & 7);
            *(uint4*)&Ps[base + ((s0 ^ sw) << 4)] = srcv[0];
            *(uint4*)&Ps[base + ((s1 ^ sw) << 4)] = srcv[1];
            float mb = mBf[l6];
            #pragma unroll
            for (int e = 0; e < 16; ++e) pk[e] = f2bf(ex2(vb[e] - mb));
            *(uint4*)&Qs[base + ((s0 ^ sw) << 4)] = srcv[0];
            *(uint4*)&Qs[base + ((s1 ^ sw) << 4)] = srcv[1];
        }
        __syncthreads();

        int w = q, lr = l6 & 15, lg = l6 >> 4;
        int brow = w * 16 + lr;
        short8 bfr[2];
        #pragma unroll
        for (int ks = 0; ks < 2; ++ks)
            bfr[ks] = *(const short8*)(Qs + brow * 128 + (((ks * 4 + lg) << 4) ^ ((brow & 7) << 4)));
        #pragma unroll
        for (int rm = 0; rm < 4; ++rm) {
            f32x4 acc = {0.f, 0.f, 0.f, 0.f};
            int ar = rm * 16 + lr;
            #pragma unroll
            for (int ks = 0; ks < 2; ++ks) {
                short8 af = *(const short8*)(Ps + ar * 128 + (((ks * 4 + lg) << 4) ^ ((ar & 7) << 4)));
                acc = __builtin_amdgcn_mfma_f32_16x16x32_bf16(af, bfr[ks], acc, 0, 0, 0);
            }
            #pragma unroll
            for (int e = 0; e < 4; ++e) {
                int ii = rm * 16 + lg * 4 + e;
                int jj = w * 16 + lr;
                Rb[ii][jj] = mA2[ii] + mB2[jj] + lg2(fmaxf(acc[e], 1e-33f));
            }
        }
        __syncthreads();
        if (s < 3) {
            #pragma unroll
            for (int jj = 0; jj < 16; ++jj)
                va[jj] = Rb[l6][q * 16 + jj];
        }
    }

    // a0 (raw start, normalization applied as scalar at the end) and final lse
    if (tid < 64) {
        int v0 = text[b * TTT];
        int s0 = w2s[v0 * SPWW];
        a0[tid] = startv[s0 + tid] * LOG2E + Ew2[(size_t)v0 * 64 + tid] - lse_em2[s0 + tid];
    }
    __syncthreads();
    float m = -3e38f, s = 0.f;
    for (int e = tid; e < 4096; e += 256) {
        float v = a0[e >> 6] + Rb[e >> 6][e & 63];
        float mn = fmaxf(m, v);
        s = s * ex2(m - mn) + ex2(v - mn);
        m = mn;
    }
    #pragma unroll
    for (int d = 32; d; d >>= 1) {
        float m2 = __shfl_xor(m, d), sx = __shfl_xor(s, d);
        float mn = fmaxf(m, m2);
        s = s * ex2(m - mn) + sx * ex2(m2 - mn); m = mn;
    }
    if ((tid & 63) == 0) { rm_[tid >> 6] = m; rs_[tid >> 6] = s; }
    __syncthreads();
    if (tid == 0) {
        float M_ = rm_[0], S_ = rs_[0];
        #pragma unroll
        for (int qq = 1; qq < 4; ++qq) {
            float mn = fmaxf(M_, rm_[qq]);
            S_ = S_ * ex2(M_ - mn) + rs_[qq] * ex2(rm_[qq] - mn); M_ = mn;
        }
        out[b] = (M_ + lg2(S_) - lse_start_s) * LN2;
    }
}

extern "C" void kernel_launch(void* const* d_in, const int* in_sizes, int n_in,
                              void* d_out, int out_size, void* d_ws, size_t ws_size,
                              hipStream_t stream) {
    const int* text        = (const int*)d_in[0];
    const int* w2s         = (const int*)d_in[1];
    const float* se1_start = (const float*)d_in[2];
    const float* se2_start = (const float*)d_in[3];
    const float* start_w1  = (const float*)d_in[4];
    const float* start_b1  = (const float*)d_in[5];
    const float* start_w2  = (const float*)d_in[6];
    const float* start_b2  = (const float*)d_in[7];
    const float* start_pw  = (const float*)d_in[8];
    const float* start_pb  = (const float*)d_in[9];
    const float* se1_state = (const float*)d_in[10];
    const float* se2_state = (const float*)d_in[11];
    const float* se1_next  = (const float*)d_in[12];
    const float* se2_next  = (const float*)d_in[13];
    const float* trans_w1  = (const float*)d_in[14];
    const float* trans_b1  = (const float*)d_in[15];
    const float* trans_w2  = (const float*)d_in[16];
    const float* trans_b2  = (const float*)d_in[17];
    const float* se1_pre   = (const float*)d_in[18];
    const float* se2_pre   = (const float*)d_in[19];
    const float* term_w1   = (const float*)d_in[20];
    const float* term_b1   = (const float*)d_in[21];
    const float* term_w2   = (const float*)d_in[22];
    const float* term_b2   = (const float*)d_in[23];
    const float* term_pw   = (const float*)d_in[24];
    const float* term_pb   = (const float*)d_in[25];
    float* out = (float*)d_out;

    char* wp = (char*)d_ws;
    auto alloc = [&](size_t bytes) {
        char* p = wp;
        wp += (bytes + 255) & ~(size_t)255;
        return (void*)p;
    };
    u16* h1a         = (u16*)alloc((size_t)CST * HH * 2);
    u16* h1b         = (u16*)alloc((size_t)CST * HH * 2);
    u16* h1c         = (u16*)alloc((size_t)CST * HH * 2);
    u16* h_state_bf  = (u16*)alloc((size_t)CST * HH * 2);
    u16* h_pre_bf    = (u16*)alloc((size_t)CST * HH * 2);
    u16* Wt          = (u16*)alloc((size_t)6 * HH * HH * 2);
    u16* pwT         = (u16*)alloc((size_t)VV * HH * 2);
    u16* e1n_bf      = (u16*)alloc((size_t)NCC * HH * 2);
    u16* e2n_bf      = (u16*)alloc((size_t)SPWW * HH * 2);
    float* U2        = (float*)alloc((size_t)CST * NCC * 4);
    float* V2        = (float*)alloc((size_t)CST * SPWW * 4);
    float* startv    = (float*)alloc(CST * 4);
    float* lse_trans = (float*)alloc(CST * 4);
    float* lse_em    = (float*)alloc(CST * 4);
    float* Ew        = (float*)alloc((size_t)VV * 64 * 4);
    int* counts      = (int*)alloc(NCC * 4);
    int* wlist       = (int*)alloc((size_t)NCC * 256 * 4);
    float* LvA       = (float*)alloc((size_t)BBB * 64 * 4096 * 4);
    float* LvB       = (float*)alloc((size_t)BBB * 16 * 4096 * 4);
    float* LvC       = (float*)alloc((size_t)BBB * 4 * 4096 * 4);
    u16* dummyY      = (u16*)alloc(256 * 2);

    // ---- mega setup (wordlist now 128 parallel class-bin blocks) ----
    SetupA sa;
    sa.Ws[0] = start_w1; sa.Ws[1] = start_w2; sa.Ws[2] = trans_w1;
    sa.Ws[3] = trans_w2; sa.Ws[4] = term_w1;  sa.Ws[5] = term_w2;
    sa.Wt = Wt; sa.pw = term_pw; sa.pwT = pwT;
    sa.e1n = se1_next; sa.e2n = se2_next; sa.e1nb = e1n_bf; sa.e2nb = e2n_bf;
    sa.w2s = w2s; sa.counts = counts; sa.wlist = wlist;
    sa.startv = startv;
    hipLaunchKernelGGL(fhmm_setup, dim3(1012), 256, 0, stream, sa);

    // ---- batched MLP layer 1 (emb on the fly) ----
    MlpA m1;
    m1.X[0] = m1.X[1] = m1.X[2] = nullptr;
    m1.se1[0] = se1_start; m1.se1[1] = se1_state; m1.se1[2] = se1_pre;
    m1.se2[0] = se2_start; m1.se2[1] = se2_state; m1.se2[2] = se2_pre;
    m1.Wth[0] = Wt + 0 * HH * HH; m1.Wth[1] = Wt + 2 * HH * HH; m1.Wth[2] = Wt + 4 * HH * HH;
    m1.bias[0] = start_b1; m1.bias[1] = trans_b1; m1.bias[2] = term_b1;
    m1.Y[0] = h1a; m1.Y[1] = h1b; m1.Y[2] = h1c;
    m1.oscale[0] = m1.oscale[1] = m1.oscale[2] = 1.0f;
    m1.pw = start_pw; m1.startv = startv;
    hipLaunchKernelGGL((fhmm_mlp_batch<0>), dim3(128, 4, 3), 256, 0, stream, m1);

    // ---- batched MLP layer 2 (residual on the fly; head0 -> startv atomics) ----
    MlpA m2 = m1;
    m2.X[0] = h1a; m2.X[1] = h1b; m2.X[2] = h1c;
    m2.Wth[0] = Wt + 1 * HH * HH; m2.Wth[1] = Wt + 3 * HH * HH; m2.Wth[2] = Wt + 5 * HH * HH;
    m2.bias[0] = start_b2; m2.bias[1] = trans_b2; m2.bias[2] = term_b2;
    m2.Y[0] = dummyY; m2.Y[1] = h_state_bf; m2.Y[2] = h_pre_bf;
    m2.oscale[0] = 1.0f; m2.oscale[1] = LOG2E; m2.oscale[2] = 1.0f;
    hipLaunchKernelGGL((fhmm_mlp_batch<1>), dim3(128, 4, 3), 256, 0, stream, m2);

    // ---- U/V GEMMs + fused row-lse ----
    hipLaunchKernelGGL(fhmm_gemm_uv_lse, dim3(128), 256, 0, stream,
                       h_state_bf, e1n_bf, e2n_bf, U2, V2, lse_trans);

    // ---- emission (Ew2 + fused lse_em2) ----
    hipLaunchKernelGGL(fhmm_ew_mfma, dim3(NCC), 256, 0, stream,
                       h_pre_bf, pwT, term_pb, wlist, counts, Ew, lse_em);

    // ---- 4-ary tree ----
    hipLaunchKernelGGL((fhmm_combine4<1>), dim3(64, BBB), 256, 0, stream,
                       U2, V2, Ew, lse_em, lse_trans, text, w2s,
                       (const float*)nullptr, LvA);
    hipLaunchKernelGGL((fhmm_combine4<0>), dim3(16, BBB), 256, 0, stream,
                       (const float*)nullptr, (const float*)nullptr,
                       (const float*)nullptr, (const float*)nullptr,
                       (const float*)nullptr, (const int*)nullptr,
                       (const int*)nullptr, LvA, LvB);
    hipLaunchKernelGGL((fhmm_combine4<0>), dim3(4, BBB), 256, 0, stream,
                       (const float*)nullptr, (const float*)nullptr,
                       (const float*)nullptr, (const float*)nullptr,
                       (const float*)nullptr, (const int*)nullptr,
                       (const int*)nullptr, LvB, LvC);

    // ---- last tree level + start-lse + final lse ----
    hipLaunchKernelGGL(fhmm_tree_final, dim3(BBB), 256, 0, stream,
                       LvC, startv, Ew, lse_em, text, w2s, out);
}

// Round 14
// 108.962 us; speedup vs baseline: 1.1614x; 1.0623x over previous
//
#include <hip/hip_runtime.h>
#include <hip/hip_bf16.h>
#include <math.h>

#define HH 256
#define NCC 128
#define SPWW 64
#define CST 8192
#define VV 10000
#define BBB 16
#define TTT 256
#define LOG2E 1.4426950408889634f
#define LN2 0.6931471805599453f

typedef __attribute__((ext_vector_type(8))) short short8;
typedef __attribute__((ext_vector_type(4))) float f32x4;
typedef unsigned short u16;

__device__ inline float bf2f(u16 u) {
    union { unsigned int i; float f; } v; v.i = ((unsigned int)u) << 16; return v.f;
}
__device__ inline u16 f2bf(float f) {
    __hip_bfloat16 h = __float2bfloat16(f);
    return *reinterpret_cast<u16*>(&h);
}
__device__ inline float ex2(float x) { return __builtin_amdgcn_exp2f(x); }
__device__ inline float lg2(float x) { return __builtin_amdgcn_logf(x); }   // v_log_f32 = log2

// ================= mega-setup: wtrans(96) + pwtrans(628) + embnext(128) + zero-startv(32) + class-bin(128) =================
struct SetupA {
    const float* Ws[6]; u16* Wt;
    const float* pw; u16* pwT;
    const float* e1n; const float* e2n; u16* e1nb; u16* e2nb;
    const int* w2s; int* counts; int* wlist;
    float* startv;
};
__global__ __launch_bounds__(256) void fhmm_setup(SetupA a)
{
    __shared__ float t[64][65];
    int blk = blockIdx.x, tid = threadIdx.x;
    if (blk < 96) {
        int z = blk >> 4, r = blk & 15;
        int k0 = (r & 3) * 64, n0 = (r >> 2) * 64;
        const float* W = a.Ws[z];
        u16* dst = a.Wt + (size_t)z * HH * HH;
        #pragma unroll
        for (int i = 0; i < 16; ++i) {
            int idx = tid + i * 256; int rr = idx >> 6, c = idx & 63;
            t[rr][c] = W[(k0 + rr) * HH + n0 + c];
        }
        __syncthreads();
        #pragma unroll
        for (int i = 0; i < 16; ++i) {
            int idx = tid + i * 256; int rr = idx >> 6, c = idx & 63;
            dst[(n0 + rr) * HH + k0 + c] = f2bf(t[c][rr]);
        }
    } else if (blk < 724) {
        int idx = blk - 96;
        int v0 = (idx % 157) * 64, k0 = (idx / 157) * 64;
        #pragma unroll
        for (int i = 0; i < 16; ++i) {
            int id2 = tid + i * 256; int rr = id2 >> 6, c = id2 & 63;   // rr:k, c:v
            int v = v0 + c;
            t[rr][c] = (v < VV) ? a.pw[(size_t)(k0 + rr) * VV + v] : 0.f;
        }
        __syncthreads();
        #pragma unroll
        for (int i = 0; i < 16; ++i) {
            int id2 = tid + i * 256; int rr = id2 >> 6, c = id2 & 63;   // rr:v, c:k
            int v = v0 + rr;
            if (v < VV) a.pwT[(size_t)v * HH + k0 + c] = f2bf(t[c][rr]);
        }
    } else if (blk < 852) {
        int idx = (blk - 724) * 256 + tid;
        if (idx < NCC * HH) a.e1nb[idx] = f2bf(a.e1n[idx]);
        if (idx < SPWW * HH) a.e2nb[idx] = f2bf(a.e2n[idx]);
    } else if (blk < 884) {
        int idx = (blk - 852) * 256 + tid;
        if (idx < CST) a.startv[idx] = 0.f;
    } else {
        int c = blk - 884;
        __shared__ int cnt;
        if (tid == 0) cnt = 0;
        __syncthreads();
        for (int v = tid; v < VV; v += 256) {
            if ((a.w2s[v * SPWW] >> 6) == c) {
                int pos = atomicAdd(&cnt, 1);
                a.wlist[c * 256 + pos] = v;
            }
        }
        __syncthreads();
        if (tid == 0) a.counts[c] = cnt;
    }
}

// ================= batched MFMA MLP (3 heads per launch) =================
struct MlpA {
    const u16* X[3];
    const float* se1[3]; const float* se2[3];
    const u16* Wth[3];
    const float* bias[3];
    u16* Y[3];
    float oscale[3];
    const float* pw;
    float* startv;
};
template<int LAYER>
__global__ __launch_bounds__(256) void fhmm_mlp_batch(MlpA a)
{
    int hd = blockIdx.z;
    int m0 = blockIdx.x * 64, n0 = blockIdx.y * 64;
    __shared__ char Xs[32768];
    __shared__ char Ws[32768];
    int tid = threadIdx.x, w = tid >> 6, lane = tid & 63, lr = lane & 15, lg = lane >> 4;
    const char* wsrc = (const char*)(a.Wth[hd] + (size_t)n0 * HH);
    if (LAYER == 0) {
        const float* s1 = a.se1[hd];
        const float* s2 = a.se2[hd];
        #pragma unroll
        for (int i = 0; i < 8; ++i) {
            int cc = i * 256 + tid; int row = cc >> 5, tt = cc & 31;
            int gm = m0 + row, k = tt * 8;
            const float* p1 = s1 + (gm >> 6) * HH + k;
            const float* p2 = s2 + (gm & 63) * HH + k;
            u16 pk[8];
            #pragma unroll
            for (int e = 0; e < 8; ++e) pk[e] = f2bf(p1[e] + p2[e]);
            int dst = row * 512 + ((tt ^ (row & 7)) << 4);
            *(uint4*)&Xs[dst] = *(uint4*)pk;
            *(uint4*)&Ws[dst] = *(const uint4*)(wsrc + cc * 16);
        }
    } else {
        const char* xsrc = (const char*)(a.X[hd] + (size_t)m0 * HH);
        #pragma unroll
        for (int i = 0; i < 8; ++i) {
            int cc = i * 256 + tid; int row = cc >> 5, tt = cc & 31;
            int dst = row * 512 + ((tt ^ (row & 7)) << 4);
            *(uint4*)&Xs[dst] = *(const uint4*)(xsrc + cc * 16);
            *(uint4*)&Ws[dst] = *(const uint4*)(wsrc + cc * 16);
        }
    }
    __syncthreads();
    short8 bfr[8];
    int brow = w * 16 + lr, bb = brow * 512, bsw = (brow & 7) << 4;
    #pragma unroll
    for (int ks = 0; ks < 8; ++ks)
        bfr[ks] = *(const short8*)(Ws + bb + (((ks * 4 + lg) << 4) ^ bsw));
    int cb = w * 16 + lg * 4;
    f32x4 bv = *(const f32x4*)(a.bias[hd] + n0 + cb);
    float osc = a.oscale[hd];
    u16* Yp = a.Y[hd];
    #pragma unroll
    for (int rm = 0; rm < 4; ++rm) {
        f32x4 acc = {0.f, 0.f, 0.f, 0.f};
        int ar = rm * 16 + lr, ab = ar * 512, asw = (ar & 7) << 4;
        #pragma unroll
        for (int ks = 0; ks < 8; ++ks) {
            short8 af = *(const short8*)(Xs + ab + (((ks * 4 + lg) << 4) ^ asw));
            acc = __builtin_amdgcn_mfma_f32_16x16x32_bf16(bfr[ks], af, acc, 0, 0, 0);
        }
        int gm = m0 + rm * 16 + lr;
        if (LAYER == 1) {
            const float* r1 = a.se1[hd] + (gm >> 6) * HH + n0 + cb;
            const float* r2 = a.se2[hd] + (gm & 63) * HH + n0 + cb;
            float vals[4];
            #pragma unroll
            for (int e = 0; e < 4; ++e)
                vals[e] = fmaxf(acc[e] + bv[e], 0.f) + r1[e] + r2[e];
            if (hd == 0) {
                const float* pwc = a.pw + n0 + cb;
                float dotp = vals[0] * pwc[0] + vals[1] * pwc[1]
                           + vals[2] * pwc[2] + vals[3] * pwc[3];
                dotp += __shfl_xor(dotp, 16);
                dotp += __shfl_xor(dotp, 32);
                if (lg == 0) atomicAdd(&a.startv[gm], dotp);
            } else {
                ushort4 o;
                #pragma unroll
                for (int e = 0; e < 4; ++e) ((u16*)&o)[e] = f2bf(vals[e] * osc);
                *(ushort4*)(Yp + (size_t)gm * HH + n0 + cb) = o;
            }
        } else {
            ushort4 o;
            #pragma unroll
            for (int e = 0; e < 4; ++e)
                ((u16*)&o)[e] = f2bf(fmaxf(acc[e] + bv[e], 0.f));
            *(ushort4*)(Yp + (size_t)gm * HH + n0 + cb) = o;
        }
    }
}

// ================= merged post kernel: blk<128 -> U/V GEMM + row-lse; blk>=128 -> emission =================
__global__ __launch_bounds__(256) void fhmm_post(
    const u16* __restrict__ Abf, const u16* __restrict__ e1n,
    const u16* __restrict__ e2n, float* __restrict__ U2, float* __restrict__ V2,
    float* __restrict__ lse_trans2,
    const u16* __restrict__ hpre_bf, const u16* __restrict__ pwT,
    const float* __restrict__ pb, const int* __restrict__ wlist,
    const int* __restrict__ counts,
    float* __restrict__ Ew2, float* __restrict__ lse_em2)
{
    __shared__ char SH[69632];
    int blk = blockIdx.x, tid = threadIdx.x;
    int w = tid >> 6, lane = tid & 63, lr = lane & 15, lg = lane >> 4;

    if (blk < 128) {
        char* Xs = SH;
        char* Ws = SH + 32768;
        float (*lmU)[64] = (float(*)[64])(SH + 65536);
        float (*lsU)[64] = (float(*)[64])(SH + 66560);
        float (*lmV)[64] = (float(*)[64])(SH + 67584);
        float (*lsV)[64] = (float(*)[64])(SH + 68608);
        int m0 = blk * 64;
        const char* xsrc = (const char*)(Abf + (size_t)m0 * HH);
        #pragma unroll
        for (int i = 0; i < 8; ++i) {
            int cc = i * 256 + tid; int row = cc >> 5, tt = cc & 31;
            int dst = row * 512 + ((tt ^ (row & 7)) << 4);
            *(uint4*)&Xs[dst] = *(const uint4*)(xsrc + cc * 16);
        }
        float mU[4], sU[4], mV[4], sV[4];
        #pragma unroll
        for (int rm = 0; rm < 4; ++rm) { mU[rm] = -3e38f; sU[rm] = 0.f; mV[rm] = -3e38f; sV[rm] = 0.f; }
        int cb = w * 16 + lg * 4;
        for (int y = 0; y < 3; ++y) {
            const char* wsrc = (y < 2) ? (const char*)(e1n + (size_t)y * 64 * HH)
                                       : (const char*)e2n;
            __syncthreads();
            #pragma unroll
            for (int i = 0; i < 8; ++i) {
                int cc = i * 256 + tid; int row = cc >> 5, tt = cc & 31;
                int dst = row * 512 + ((tt ^ (row & 7)) << 4);
                *(uint4*)&Ws[dst] = *(const uint4*)(wsrc + cc * 16);
            }
            __syncthreads();
            short8 bfr[8];
            int brow = w * 16 + lr, bb = brow * 512, bsw = (brow & 7) << 4;
            #pragma unroll
            for (int ks = 0; ks < 8; ++ks)
                bfr[ks] = *(const short8*)(Ws + bb + (((ks * 4 + lg) << 4) ^ bsw));
            #pragma unroll
            for (int rm = 0; rm < 4; ++rm) {
                f32x4 acc = {0.f, 0.f, 0.f, 0.f};
                int ar = rm * 16 + lr, ab = ar * 512, asw = (ar & 7) << 4;
                #pragma unroll
                for (int ks = 0; ks < 8; ++ks) {
                    short8 af = *(const short8*)(Xs + ab + (((ks * 4 + lg) << 4) ^ asw));
                    acc = __builtin_amdgcn_mfma_f32_16x16x32_bf16(bfr[ks], af, acc, 0, 0, 0);
                }
                int gm = m0 + rm * 16 + lr;
                float lm = fmaxf(fmaxf(acc[0], acc[1]), fmaxf(acc[2], acc[3]));
                if (y < 2) {
                    *(f32x4*)(U2 + (size_t)gm * NCC + y * 64 + cb) = acc;
                    float mn = fmaxf(mU[rm], lm);
                    sU[rm] = sU[rm] * ex2(mU[rm] - mn)
                           + ex2(acc[0] - mn) + ex2(acc[1] - mn)
                           + ex2(acc[2] - mn) + ex2(acc[3] - mn);
                    mU[rm] = mn;
                } else {
                    *(f32x4*)(V2 + (size_t)gm * SPWW + cb) = acc;
                    float mn = fmaxf(mV[rm], lm);
                    sV[rm] = sV[rm] * ex2(mV[rm] - mn)
                           + ex2(acc[0] - mn) + ex2(acc[1] - mn)
                           + ex2(acc[2] - mn) + ex2(acc[3] - mn);
                    mV[rm] = mn;
                }
            }
        }
        #pragma unroll
        for (int rm = 0; rm < 4; ++rm) {
            #pragma unroll
            for (int d = 16; d < 64; d <<= 1) {
                float m2 = __shfl_xor(mU[rm], d), sx = __shfl_xor(sU[rm], d);
                float mn = fmaxf(mU[rm], m2);
                sU[rm] = sU[rm] * ex2(mU[rm] - mn) + sx * ex2(m2 - mn); mU[rm] = mn;
                m2 = __shfl_xor(mV[rm], d); sx = __shfl_xor(sV[rm], d);
                mn = fmaxf(mV[rm], m2);
                sV[rm] = sV[rm] * ex2(mV[rm] - mn) + sx * ex2(m2 - mn); mV[rm] = mn;
            }
        }
        __syncthreads();
        if (lg == 0) {
            #pragma unroll
            for (int rm = 0; rm < 4; ++rm) {
                lmU[w][rm * 16 + lr] = mU[rm]; lsU[w][rm * 16 + lr] = sU[rm];
                lmV[w][rm * 16 + lr] = mV[rm]; lsV[w][rm * 16 + lr] = sV[rm];
            }
        }
        __syncthreads();
        if (tid < 64) {
            float MU = lmU[0][tid], SU = lsU[0][tid];
            float MV = lmV[0][tid], SV = lsV[0][tid];
            #pragma unroll
            for (int q = 1; q < 4; ++q) {
                float m2 = lmU[q][tid], sx = lsU[q][tid];
                float mn = fmaxf(MU, m2);
                SU = SU * ex2(MU - mn) + sx * ex2(m2 - mn); MU = mn;
                m2 = lmV[q][tid]; sx = lsV[q][tid];
                mn = fmaxf(MV, m2);
                SV = SV * ex2(MV - mn) + sx * ex2(m2 - mn); MV = mn;
            }
            lse_trans2[m0 + tid] = (MU + lg2(SU)) + (MV + lg2(SV));
        }
    } else {
        char* Hs = SH;
        float (*emM)[64] = (float(*)[64])(SH + 32768);
        float (*emS)[64] = (float(*)[64])(SH + 33792);
        int c = blk - 128;
        int cnt = counts[c], off = c * 256;
        const char* src = (const char*)(hpre_bf + (size_t)c * 64 * HH);
        #pragma unroll
        for (int i = 0; i < 8; ++i) {
            int cc = i * 256 + tid; int row = cc >> 5, tt = cc & 31;
            *(uint4*)&Hs[row * 512 + ((tt ^ (row & 7)) << 4)] = *(const uint4*)(src + cc * 16);
        }
        __syncthreads();
        float em_m[4][4], em_s[4][4];
        #pragma unroll
        for (int rm = 0; rm < 4; ++rm)
            #pragma unroll
            for (int e = 0; e < 4; ++e) { em_m[rm][e] = -3e38f; em_s[rm][e] = 0.f; }
        for (int ch = 0; ch * 64 < cnt; ++ch) {
            int widx = ch * 64 + w * 16 + lr;
            bool valid = widx < cnt;
            int v = valid ? wlist[off + widx] : 0;
            short8 bw[8];
            short8 bz = {0, 0, 0, 0, 0, 0, 0, 0};
            #pragma unroll
            for (int ks = 0; ks < 8; ++ks)
                bw[ks] = valid ? *(const short8*)(pwT + (size_t)v * HH + ks * 32 + lg * 8) : bz;
            float pbv = valid ? pb[v] : 0.f;
            #pragma unroll
            for (int rm = 0; rm < 4; ++rm) {
                f32x4 acc = {0.f, 0.f, 0.f, 0.f};
                int ar = rm * 16 + lr, ab = ar * 512, asw = (ar & 7) << 4;
                #pragma unroll
                for (int ks = 0; ks < 8; ++ks) {
                    short8 ah = *(const short8*)(Hs + ab + (((ks * 4 + lg) << 4) ^ asw));
                    acc = __builtin_amdgcn_mfma_f32_16x16x32_bf16(ah, bw[ks], acc, 0, 0, 0);
                }
                f32x4 o;
                #pragma unroll
                for (int e = 0; e < 4; ++e) o[e] = (acc[e] + pbv) * LOG2E;
                if (valid)
                    *(f32x4*)(Ew2 + (size_t)v * 64 + rm * 16 + lg * 4) = o;
                #pragma unroll
                for (int e = 0; e < 4; ++e) {
                    if (valid) {
                        float mn = fmaxf(em_m[rm][e], o[e]);
                        em_s[rm][e] = em_s[rm][e] * ex2(em_m[rm][e] - mn) + ex2(o[e] - mn);
                        em_m[rm][e] = mn;
                    }
                }
            }
        }
        #pragma unroll
        for (int rm = 0; rm < 4; ++rm)
            #pragma unroll
            for (int e = 0; e < 4; ++e) {
                float mm = em_m[rm][e], ss = em_s[rm][e];
                #pragma unroll
                for (int d = 1; d < 16; d <<= 1) {
                    float m2 = __shfl_xor(mm, d);
                    float s2 = __shfl_xor(ss, d);
                    float mn = fmaxf(mm, m2);
                    ss = ss * ex2(mm - mn) + s2 * ex2(m2 - mn);
                    mm = mn;
                }
                em_m[rm][e] = mm; em_s[rm][e] = ss;
            }
        if (lr == 0) {
            #pragma unroll
            for (int rm = 0; rm < 4; ++rm)
                #pragma unroll
                for (int e = 0; e < 4; ++e) {
                    emM[w][rm * 16 + lg * 4 + e] = em_m[rm][e];
                    emS[w][rm * 16 + lg * 4 + e] = em_s[rm][e];
                }
        }
        __syncthreads();
        if (tid < 64) {
            float M = emM[0][tid], S = emS[0][tid];
            #pragma unroll
            for (int q2 = 1; q2 < 4; ++q2) {
                float m2 = emM[q2][tid], s2 = emS[q2][tid];
                float mn = fmaxf(M, m2);
                S = S * ex2(M - mn) + s2 * ex2(m2 - mn); M = mn;
            }
            lse_em2[c * 64 + tid] = M + lg2(fmaxf(S, 1e-33f));
        }
    }
}

// ================= 4-ARY TREE COMBINE in lse2 semiring (obs computed inline) ==================
template<int LEAF>
__global__ __launch_bounds__(256) void fhmm_combine4(
    const float* __restrict__ U2, const float* __restrict__ V2,
    const float* __restrict__ Ew2, const float* __restrict__ lse_em2,
    const float* __restrict__ lse2,
    const int* __restrict__ text, const int* __restrict__ w2s,
    const float* __restrict__ Lin, float* __restrict__ Lout)
{
    int p = blockIdx.x, b = blockIdx.y;
    int nodes = gridDim.x;
    int tid = threadIdx.x;
    int l6 = tid & 63, q = tid >> 6;

    __shared__ float Rb[64][65];
    __shared__ char Ps[8192], Qs[8192];
    __shared__ float mA2[64], mB2[64], mAf[64], mBf[64];
    __shared__ float part[2][4][64];
    __shared__ float rtB_l[64];

    int nm = LEAF ? ((p == 63) ? 3 : 4) : 4;
    int t0 = 4 * p + 1;
    int in0 = 4 * p;

    float va[16];
    float rowA = 0.f;

    if (LEAF) {
        int vprev = text[b * TTT + (t0 - 1)];
        int vA = text[b * TTT + t0];
        int srA = w2s[vprev * SPWW];
        int sA = w2s[vA * SPWW];          // = 64*cA
        int cA = sA >> 6;
        rowA = U2[(size_t)(srA + l6) * NCC + cA] - lse2[srA + l6];
        const float* vrow = V2 + (size_t)(srA + l6) * SPWW;
        const float* ewA = Ew2 + (size_t)vA * 64;
        const float* leA = lse_em2 + sA;
        #pragma unroll
        for (int jj = 0; jj < 16; ++jj) {
            int j = q * 16 + jj;
            va[jj] = vrow[j] + ewA[j] - leA[j];
        }
    } else {
        const float* Af = Lin + ((size_t)(b * (4 * nodes) + in0)) * 4096;
        #pragma unroll
        for (int jj = 0; jj < 16; ++jj)
            va[jj] = Af[l6 * 64 + q * 16 + jj];
    }

    for (int s = 1; s < nm; ++s) {
        float mloc = -3e38f;
        #pragma unroll
        for (int jj = 0; jj < 16; ++jj) mloc = fmaxf(mloc, va[jj]);
        part[0][q][l6] = mloc;

        float vb[16], obB = 0.f;
        if (LEAF) {
            int tB = t0 + s;
            int vBp = text[b * TTT + (tB - 1)];
            int vB = text[b * TTT + tB];
            int srB = w2s[vBp * SPWW];
            int sB = w2s[vB * SPWW];
            int cB = sB >> 6;
            if (tid < 64)
                rtB_l[tid] = U2[(size_t)(srB + tid) * NCC + cB] - lse2[srB + tid];
            obB = Ew2[(size_t)vB * 64 + l6] - lse_em2[sB + l6];
            float vraw[16];
            #pragma unroll
            for (int kk = 0; kk < 16; ++kk)
                vraw[kk] = V2[(size_t)(srB + q * 16 + kk) * SPWW + l6];
            __syncthreads();
            float mlocB = -3e38f;
            #pragma unroll
            for (int kk = 0; kk < 16; ++kk) {
                vb[kk] = vraw[kk] + rtB_l[q * 16 + kk];
                mlocB = fmaxf(mlocB, vb[kk]);
            }
            part[1][q][l6] = mlocB;
        } else {
            const float* Bf = Lin + ((size_t)(b * (4 * nodes) + in0 + s)) * 4096;
            float mlocB = -3e38f;
            #pragma unroll
            for (int kk = 0; kk < 16; ++kk) {
                float v = Bf[(q * 16 + kk) * 64 + l6];
                vb[kk] = v; mlocB = fmaxf(mlocB, v);
            }
            part[1][q][l6] = mlocB;
        }
        __syncthreads();

        if (tid < 64) {
            float mf = fmaxf(fmaxf(part[0][0][tid], part[0][1][tid]),
                             fmaxf(part[0][2][tid], part[0][3][tid]));
            mAf[tid] = mf;
            mA2[tid] = mf + ((LEAF && s == 1) ? rowA : 0.f);
        } else if (tid < 128) {
            int j = tid & 63;
            float mf = fmaxf(fmaxf(part[1][0][j], part[1][1][j]),
                             fmaxf(part[1][2][j], part[1][3][j]));
            mBf[j] = mf;
            mB2[j] = mf + obB;
        }
        __syncthreads();

        {
            float ma = mAf[l6];
            u16 pk[16];
            #pragma unroll
            for (int e = 0; e < 16; ++e) pk[e] = f2bf(ex2(va[e] - ma));
            uint4* srcv = (uint4*)pk;
            int base = l6 * 128;
            int s0 = 2 * q, s1 = 2 * q + 1, sw = (l6 & 7);
            *(uint4*)&Ps[base + ((s0 ^ sw) << 4)] = srcv[0];
            *(uint4*)&Ps[base + ((s1 ^ sw) << 4)] = srcv[1];
            float mb = mBf[l6];
            #pragma unroll
            for (int e = 0; e < 16; ++e) pk[e] = f2bf(ex2(vb[e] - mb));
            *(uint4*)&Qs[base + ((s0 ^ sw) << 4)] = srcv[0];
            *(uint4*)&Qs[base + ((s1 ^ sw) << 4)] = srcv[1];
        }
        __syncthreads();

        int w = q, lr = l6 & 15, lg = l6 >> 4;
        int brow = w * 16 + lr;
        short8 bfr[2];
        #pragma unroll
        for (int ks = 0; ks < 2; ++ks)
            bfr[ks] = *(const short8*)(Qs + brow * 128 + (((ks * 4 + lg) << 4) ^ ((brow & 7) << 4)));
        bool last = (s == nm - 1);
        float* Co = Lout + ((size_t)(b * nodes + p)) * 4096;
        #pragma unroll
        for (int rm = 0; rm < 4; ++rm) {
            f32x4 acc = {0.f, 0.f, 0.f, 0.f};
            int ar = rm * 16 + lr;
            #pragma unroll
            for (int ks = 0; ks < 2; ++ks) {
                short8 af = *(const short8*)(Ps + ar * 128 + (((ks * 4 + lg) << 4) ^ ((ar & 7) << 4)));
                acc = __builtin_amdgcn_mfma_f32_16x16x32_bf16(af, bfr[ks], acc, 0, 0, 0);
            }
            #pragma unroll
            for (int e = 0; e < 4; ++e) {
                int ii = rm * 16 + lg * 4 + e;
                int jj = w * 16 + lr;
                float cv = mA2[ii] + mB2[jj] + lg2(fmaxf(acc[e], 1e-33f));
                if (last) Co[ii * 64 + jj] = cv;
                else      Rb[ii][jj] = cv;
            }
        }
        if (!last) {
            __syncthreads();
            #pragma unroll
            for (int jj = 0; jj < 16; ++jj)
                va[jj] = Rb[l6][q * 16 + jj];
        }
    }
}

// ================= fused last tree level + start-lse + final lse ==================
__global__ __launch_bounds__(256) void fhmm_tree_final(
    const float* __restrict__ Lin,
    const float* __restrict__ startv, const float* __restrict__ Ew2,
    const float* __restrict__ lse_em2,
    const int* __restrict__ text, const int* __restrict__ w2s,
    float* __restrict__ out)
{
    int b = blockIdx.x;
    int tid = threadIdx.x;
    int l6 = tid & 63, q = tid >> 6;

    __shared__ float Rb[64][65];
    __shared__ char Ps[8192], Qs[8192];
    __shared__ float mA2[64], mB2[64], mAf[64], mBf[64];
    __shared__ float part[2][4][64];
    __shared__ float a0[64];
    __shared__ float rm_[4], rs_[4];
    __shared__ float lse_start_s;

    // ---- global lse2 of raw start logits (pb cancels in log_softmax) ----
    {
        float m = -3e38f, s = 0.f;
        for (int i = tid; i < CST; i += 256) {
            float v = startv[i] * LOG2E;
            float mn = fmaxf(m, v);
            s = s * ex2(m - mn) + ex2(v - mn);
            m = mn;
        }
        #pragma unroll
        for (int d = 32; d; d >>= 1) {
            float m2 = __shfl_xor(m, d), sx = __shfl_xor(s, d);
            float mn = fmaxf(m, m2);
            s = s * ex2(m - mn) + sx * ex2(m2 - mn); m = mn;
        }
        if ((tid & 63) == 0) { rm_[tid >> 6] = m; rs_[tid >> 6] = s; }
        __syncthreads();
        if (tid == 0) {
            float M_ = rm_[0], S_ = rs_[0];
            #pragma unroll
            for (int qq = 1; qq < 4; ++qq) {
                float mn = fmaxf(M_, rm_[qq]);
                S_ = S_ * ex2(M_ - mn) + rs_[qq] * ex2(rm_[qq] - mn); M_ = mn;
            }
            lse_start_s = M_ + lg2(S_);
        }
        __syncthreads();
    }

    float va[16];
    {
        const float* Af = Lin + ((size_t)(b * 4)) * 4096;
        #pragma unroll
        for (int jj = 0; jj < 16; ++jj)
            va[jj] = Af[l6 * 64 + q * 16 + jj];
    }

    for (int s = 1; s < 4; ++s) {
        float mloc = -3e38f;
        #pragma unroll
        for (int jj = 0; jj < 16; ++jj) mloc = fmaxf(mloc, va[jj]);
        part[0][q][l6] = mloc;

        const float* Bf = Lin + ((size_t)(b * 4 + s)) * 4096;
        float vb[16];
        float mlocB = -3e38f;
        #pragma unroll
        for (int kk = 0; kk < 16; ++kk) {
            float v = Bf[(q * 16 + kk) * 64 + l6];
            vb[kk] = v; mlocB = fmaxf(mlocB, v);
        }
        part[1][q][l6] = mlocB;
        __syncthreads();

        if (tid < 64) {
            float mf = fmaxf(fmaxf(part[0][0][tid], part[0][1][tid]),
                             fmaxf(part[0][2][tid], part[0][3][tid]));
            mAf[tid] = mf; mA2[tid] = mf;
        } else if (tid < 128) {
            int j = tid & 63;
            float mf = fmaxf(fmaxf(part[1][0][j], part[1][1][j]),
                             fmaxf(part[1][2][j], part[1][3][j]));
            mBf[j] = mf; mB2[j] = mf;
        }
        __syncthreads();

        {
            float ma = mAf[l6];
            u16 pk[16];
            #pragma unroll
            for (int e = 0; e < 16; ++e) pk[e] = f2bf(ex2(va[e] - ma));
            uint4* srcv = (uint4*)pk;
            int base = l6 * 128;
            int s0 = 2 * q, s1 = 2 * q + 1, sw = (l6 & 7);
            *(uint4*)&Ps[base + ((s0 ^ sw) << 4)] = srcv[0];
            *(uint4*)&Ps[base + ((s1 ^ sw) << 4)] = srcv[1];
            float mb = mBf[l6];
            #pragma unroll
            for (int e = 0; e < 16; ++e) pk[e] = f2bf(ex2(vb[e] - mb));
            *(uint4*)&Qs[base + ((s0 ^ sw) << 4)] = srcv[0];
            *(uint4*)&Qs[base + ((s1 ^ sw) << 4)] = srcv[1];
        }
        __syncthreads();

        int w = q, lr = l6 & 15, lg = l6 >> 4;
        int brow = w * 16 + lr;
        short8 bfr[2];
        #pragma unroll
        for (int ks = 0; ks < 2; ++ks)
            bfr[ks] = *(const short8*)(Qs + brow * 128 + (((ks * 4 + lg) << 4) ^ ((brow & 7) << 4)));
        #pragma unroll
        for (int rm = 0; rm < 4; ++rm) {
            f32x4 acc = {0.f, 0.f, 0.f, 0.f};
            int ar = rm * 16 + lr;
            #pragma unroll
            for (int ks = 0; ks < 2; ++ks) {
                short8 af = *(const short8*)(Ps + ar * 128 + (((ks * 4 + lg) << 4) ^ ((ar & 7) << 4)));
                acc = __builtin_amdgcn_mfma_f32_16x16x32_bf16(af, bfr[ks], acc, 0, 0, 0);
            }
            #pragma unroll
            for (int e = 0; e < 4; ++e) {
                int ii = rm * 16 + lg * 4 + e;
                int jj = w * 16 + lr;
                Rb[ii][jj] = mA2[ii] + mB2[jj] + lg2(fmaxf(acc[e], 1e-33f));
            }
        }
        __syncthreads();
        if (s < 3) {
            #pragma unroll
            for (int jj = 0; jj < 16; ++jj)
                va[jj] = Rb[l6][q * 16 + jj];
        }
    }

    // a0 (raw start, normalization applied as scalar at the end) and final lse
    if (tid < 64) {
        int v0 = text[b * TTT];
        int s0 = w2s[v0 * SPWW];
        a0[tid] = startv[s0 + tid] * LOG2E + Ew2[(size_t)v0 * 64 + tid] - lse_em2[s0 + tid];
    }
    __syncthreads();
    float m = -3e38f, s = 0.f;
    for (int e = tid; e < 4096; e += 256) {
        float v = a0[e >> 6] + Rb[e >> 6][e & 63];
        float mn = fmaxf(m, v);
        s = s * ex2(m - mn) + ex2(v - mn);
        m = mn;
    }
    #pragma unroll
    for (int d = 32; d; d >>= 1) {
        float m2 = __shfl_xor(m, d), sx = __shfl_xor(s, d);
        float mn = fmaxf(m, m2);
        s = s * ex2(m - mn) + sx * ex2(m2 - mn); m = mn;
    }
    if ((tid & 63) == 0) { rm_[tid >> 6] = m; rs_[tid >> 6] = s; }
    __syncthreads();
    if (tid == 0) {
        float M_ = rm_[0], S_ = rs_[0];
        #pragma unroll
        for (int qq = 1; qq < 4; ++qq) {
            float mn = fmaxf(M_, rm_[qq]);
            S_ = S_ * ex2(M_ - mn) + rs_[qq] * ex2(rm_[qq] - mn); M_ = mn;
        }
        out[b] = (M_ + lg2(S_) - lse_start_s) * LN2;
    }
}

extern "C" void kernel_launch(void* const* d_in, const int* in_sizes, int n_in,
                              void* d_out, int out_size, void* d_ws, size_t ws_size,
                              hipStream_t stream) {
    const int* text        = (const int*)d_in[0];
    const int* w2s         = (const int*)d_in[1];
    const float* se1_start = (const float*)d_in[2];
    const float* se2_start = (const float*)d_in[3];
    const float* start_w1  = (const float*)d_in[4];
    const float* start_b1  = (const float*)d_in[5];
    const float* start_w2  = (const float*)d_in[6];
    const float* start_b2  = (const float*)d_in[7];
    const float* start_pw  = (const float*)d_in[8];
    const float* start_pb  = (const float*)d_in[9];
    const float* se1_state = (const float*)d_in[10];
    const float* se2_state = (const float*)d_in[11];
    const float* se1_next  = (const float*)d_in[12];
    const float* se2_next  = (const float*)d_in[13];
    const float* trans_w1  = (const float*)d_in[14];
    const float* trans_b1  = (const float*)d_in[15];
    const float* trans_w2  = (const float*)d_in[16];
    const float* trans_b2  = (const float*)d_in[17];
    const float* se1_pre   = (const float*)d_in[18];
    const float* se2_pre   = (const float*)d_in[19];
    const float* term_w1   = (const float*)d_in[20];
    const float* term_b1   = (const float*)d_in[21];
    const float* term_w2   = (const float*)d_in[22];
    const float* term_b2   = (const float*)d_in[23];
    const float* term_pw   = (const float*)d_in[24];
    const float* term_pb   = (const float*)d_in[25];
    float* out = (float*)d_out;

    char* wp = (char*)d_ws;
    auto alloc = [&](size_t bytes) {
        char* p = wp;
        wp += (bytes + 255) & ~(size_t)255;
        return (void*)p;
    };
    u16* h1a         = (u16*)alloc((size_t)CST * HH * 2);
    u16* h1b         = (u16*)alloc((size_t)CST * HH * 2);
    u16* h1c         = (u16*)alloc((size_t)CST * HH * 2);
    u16* h_state_bf  = (u16*)alloc((size_t)CST * HH * 2);
    u16* h_pre_bf    = (u16*)alloc((size_t)CST * HH * 2);
    u16* Wt          = (u16*)alloc((size_t)6 * HH * HH * 2);
    u16* pwT         = (u16*)alloc((size_t)VV * HH * 2);
    u16* e1n_bf      = (u16*)alloc((size_t)NCC * HH * 2);
    u16* e2n_bf      = (u16*)alloc((size_t)SPWW * HH * 2);
    float* U2        = (float*)alloc((size_t)CST * NCC * 4);
    float* V2        = (float*)alloc((size_t)CST * SPWW * 4);
    float* startv    = (float*)alloc(CST * 4);
    float* lse_trans = (float*)alloc(CST * 4);
    float* lse_em    = (float*)alloc(CST * 4);
    float* Ew        = (float*)alloc((size_t)VV * 64 * 4);
    int* counts      = (int*)alloc(NCC * 4);
    int* wlist       = (int*)alloc((size_t)NCC * 256 * 4);
    float* LvA       = (float*)alloc((size_t)BBB * 64 * 4096 * 4);
    float* LvB       = (float*)alloc((size_t)BBB * 16 * 4096 * 4);
    float* LvC       = (float*)alloc((size_t)BBB * 4 * 4096 * 4);
    u16* dummyY      = (u16*)alloc(256 * 2);

    // ---- mega setup ----
    SetupA sa;
    sa.Ws[0] = start_w1; sa.Ws[1] = start_w2; sa.Ws[2] = trans_w1;
    sa.Ws[3] = trans_w2; sa.Ws[4] = term_w1;  sa.Ws[5] = term_w2;
    sa.Wt = Wt; sa.pw = term_pw; sa.pwT = pwT;
    sa.e1n = se1_next; sa.e2n = se2_next; sa.e1nb = e1n_bf; sa.e2nb = e2n_bf;
    sa.w2s = w2s; sa.counts = counts; sa.wlist = wlist;
    sa.startv = startv;
    hipLaunchKernelGGL(fhmm_setup, dim3(1012), 256, 0, stream, sa);

    // ---- batched MLP layer 1 ----
    MlpA m1;
    m1.X[0] = m1.X[1] = m1.X[2] = nullptr;
    m1.se1[0] = se1_start; m1.se1[1] = se1_state; m1.se1[2] = se1_pre;
    m1.se2[0] = se2_start; m1.se2[1] = se2_state; m1.se2[2] = se2_pre;
    m1.Wth[0] = Wt + 0 * HH * HH; m1.Wth[1] = Wt + 2 * HH * HH; m1.Wth[2] = Wt + 4 * HH * HH;
    m1.bias[0] = start_b1; m1.bias[1] = trans_b1; m1.bias[2] = term_b1;
    m1.Y[0] = h1a; m1.Y[1] = h1b; m1.Y[2] = h1c;
    m1.oscale[0] = m1.oscale[1] = m1.oscale[2] = 1.0f;
    m1.pw = start_pw; m1.startv = startv;
    hipLaunchKernelGGL((fhmm_mlp_batch<0>), dim3(128, 4, 3), 256, 0, stream, m1);

    // ---- batched MLP layer 2 (head0 -> startv atomics) ----
    MlpA m2 = m1;
    m2.X[0] = h1a; m2.X[1] = h1b; m2.X[2] = h1c;
    m2.Wth[0] = Wt + 1 * HH * HH; m2.Wth[1] = Wt + 3 * HH * HH; m2.Wth[2] = Wt + 5 * HH * HH;
    m2.bias[0] = start_b2; m2.bias[1] = trans_b2; m2.bias[2] = term_b2;
    m2.Y[0] = dummyY; m2.Y[1] = h_state_bf; m2.Y[2] = h_pre_bf;
    m2.oscale[0] = 1.0f; m2.oscale[1] = LOG2E; m2.oscale[2] = 1.0f;
    hipLaunchKernelGGL((fhmm_mlp_batch<1>), dim3(128, 4, 3), 256, 0, stream, m2);

    // ---- merged post: U/V GEMM + row-lse (blk<128) and emission (blk>=128) ----
    hipLaunchKernelGGL(fhmm_post, dim3(256), 256, 0, stream,
                       h_state_bf, e1n_bf, e2n_bf, U2, V2, lse_trans,
                       h_pre_bf, pwT, term_pb, wlist, counts, Ew, lse_em);

    // ---- 4-ary tree (regular launches; cooperative launch breaks graph capture) ----
    hipLaunchKernelGGL((fhmm_combine4<1>), dim3(64, BBB), 256, 0, stream,
                       U2, V2, Ew, lse_em, lse_trans, text, w2s,
                       (const float*)nullptr, LvA);
    hipLaunchKernelGGL((fhmm_combine4<0>), dim3(16, BBB), 256, 0, stream,
                       (const float*)nullptr, (const float*)nullptr,
                       (const float*)nullptr, (const float*)nullptr,
                       (const float*)nullptr, (const int*)nullptr,
                       (const int*)nullptr, LvA, LvB);
    hipLaunchKernelGGL((fhmm_combine4<0>), dim3(4, BBB), 256, 0, stream,
                       (const float*)nullptr, (const float*)nullptr,
                       (const float*)nullptr, (const float*)nullptr,
                       (const float*)nullptr, (const int*)nullptr,
                       (const int*)nullptr, LvB, LvC);

    // ---- last tree level + start-lse + final lse ----
    hipLaunchKernelGGL(fhmm_tree_final, dim3(BBB), 256, 0, stream,
                       LvC, startv, Ew, lse_em, text, w2s, out);
}